// Round 1
// baseline (444.634 us; speedup 1.0000x reference)
//
#include <hip/hip_runtime.h>
#include <stdint.h>

typedef unsigned short u16;
typedef unsigned int   u32;
typedef __bf16  bf16x8 __attribute__((ext_vector_type(8)));
typedef float   f32x4  __attribute__((ext_vector_type(4)));

#define LORA_SCALE 2.0f
#define QSCALE 0.08838834764831845f   // 1/sqrt(128)

__device__ __forceinline__ u16 f2bf(float f){
  u32 u = __builtin_bit_cast(u32, f);
  u32 r = (u + 0x7fffu + ((u >> 16) & 1u)) >> 16;   // RNE
  return (u16)r;
}
__device__ __forceinline__ float bf2f(u16 v){
  return __builtin_bit_cast(float, ((u32)v) << 16);
}

typedef __attribute__((address_space(3))) u32 lds_u32_t;
typedef __attribute__((address_space(1))) const u32 g_u32_t;

// async global->LDS, 16B per lane; LDS dest = wave-uniform base + lane*16
__device__ __forceinline__ void gload16(const void* g, void* l){
  __builtin_amdgcn_global_load_lds((g_u32_t*)(unsigned long long)g,
                                   (lds_u32_t*)(u32)(unsigned long long)l,
                                   16, 0, 0);
}

// ---------------- fp32 -> bf16 convert ----------------
__global__ __launch_bounds__(256) void cvt_f32_bf16(const float* __restrict__ in,
                                                    u16* __restrict__ out, int n){
  int i = (blockIdx.x * 256 + threadIdx.x) * 8;
  if (i >= n) return;
  float4 a = *(const float4*)(in + i);
  float4 b = *(const float4*)(in + i + 4);
  u16 o[8] = {f2bf(a.x),f2bf(a.y),f2bf(a.z),f2bf(a.w),
              f2bf(b.x),f2bf(b.y),f2bf(b.z),f2bf(b.w)};
  *(uint4*)(out + i) = *(const uint4*)o;
}

// ---------------- LoRA stage 1: xa[m][r] = sum_k in[m][k]*A_g[r][k] ----------------
// one wave per row m; NG A-matrices at once. fp32 exact (or bf16 ctx input).
template<int NG, int BF16IN>
__global__ __launch_bounds__(256) void lora_xa_kernel(const void* __restrict__ xin,
    const float* __restrict__ A0, const float* __restrict__ A1, const float* __restrict__ A2,
    float* __restrict__ xout){
  int w = threadIdx.x >> 6, lane = threadIdx.x & 63;
  int m = blockIdx.x * 4 + w;
  float acc[NG][8];
  #pragma unroll
  for (int g=0; g<NG; ++g)
    #pragma unroll
    for (int r=0; r<8; ++r) acc[g][r] = 0.f;
  const float* As[3] = {A0, A1, A2};
  #pragma unroll 1
  for (int it=0; it<8; ++it){
    int k = it*256 + lane*4;
    float4 xv;
    if (BF16IN){
      const u16* xp = (const u16*)xin + (size_t)m*2048 + k;
      ushort4 u = *(const ushort4*)xp;
      xv.x = bf2f(u.x); xv.y = bf2f(u.y); xv.z = bf2f(u.z); xv.w = bf2f(u.w);
    } else {
      xv = *(const float4*)((const float*)xin + (size_t)m*2048 + k);
    }
    #pragma unroll
    for (int g=0; g<NG; ++g){
      const float* Ag = As[g];
      #pragma unroll
      for (int r=0; r<8; ++r){
        float4 av = *(const float4*)(Ag + r*2048 + k);
        acc[g][r] += xv.x*av.x + xv.y*av.y + xv.z*av.z + xv.w*av.w;
      }
    }
  }
  #pragma unroll
  for (int g=0; g<NG; ++g)
    #pragma unroll
    for (int r=0; r<8; ++r){
      float v = acc[g][r];
      #pragma unroll
      for (int off=32; off; off>>=1) v += __shfl_xor(v, off);
      if (lane == 0) xout[g*32768 + m*8 + r] = v;
    }
}

// ---------------- fused GEMM: out = A @ W^T + bias + 2*(xa @ lB^T)  ----------------
// m97 structure: 128x128 tile, BK=32, 4 waves (2x2), global_load_lds w=16.
// swz=1: store bf16 output col-swizzled (col ^= (row&7)<<3) for the attention LDS path.
__global__ __launch_bounds__(256, 2) void gemm_fused(
    const u16* __restrict__ A, const u16* __restrict__ W,
    const float* __restrict__ bias, const float* __restrict__ lB,
    const float* __restrict__ xa, void* __restrict__ outp,
    int f32out, int swz, float oscale){
  const int Kd = 2048, Nd = 2048;
  __shared__ u16 Ash[128*32];
  __shared__ u16 Bsh[128*32];
  int tid = threadIdx.x, w = tid >> 6, lane = tid & 63;
  int l15 = lane & 15, l4 = lane >> 4;
  int n0 = blockIdx.x * 128, m0 = blockIdx.y * 128;
  int wm = w >> 1, wn = w & 1;
  f32x4 acc[4][4];
  #pragma unroll
  for (int mi=0; mi<4; mi++)
    #pragma unroll
    for (int ni=0; ni<4; ni++) acc[mi][ni] = (f32x4){0.f,0.f,0.f,0.f};

  const u16* Arow = A + (size_t)m0 * Kd;
  const u16* Wrow = W + (size_t)n0 * Kd;
  for (int kt = 0; kt < Kd; kt += 32){
    __syncthreads();
    #pragma unroll
    for (int i=0; i<2; ++i){
      int e = (i*256 + tid) * 8;
      int r = e >> 5, c = e & 31;
      gload16(Arow + (size_t)r*Kd + kt + c, (char*)Ash + i*4096 + w*1024);
      gload16(Wrow + (size_t)r*Kd + kt + c, (char*)Bsh + i*4096 + w*1024);
    }
    __syncthreads();
    bf16x8 af[4], bfv[4];
    #pragma unroll
    for (int mi=0; mi<4; mi++)
      af[mi] = *(const bf16x8*)(Ash + (wm*64 + mi*16 + l15)*32 + l4*8);
    #pragma unroll
    for (int ni=0; ni<4; ni++)
      bfv[ni] = *(const bf16x8*)(Bsh + (wn*64 + ni*16 + l15)*32 + l4*8);
    #pragma unroll
    for (int mi=0; mi<4; mi++)
      #pragma unroll
      for (int ni=0; ni<4; ni++)
        acc[mi][ni] = __builtin_amdgcn_mfma_f32_16x16x32_bf16(af[mi], bfv[ni], acc[mi][ni], 0, 0, 0);
  }
  // epilogue: bias + LoRA + optional scale, write fp32 or (swizzled) bf16
  float bv[4]; float4 lb0[4], lb1[4];
  #pragma unroll
  for (int ni=0; ni<4; ni++){
    int col = n0 + wn*64 + ni*16 + l15;
    bv[ni] = bias[col];
    lb0[ni] = *(const float4*)(lB + col*8);
    lb1[ni] = *(const float4*)(lB + col*8 + 4);
  }
  #pragma unroll
  for (int mi=0; mi<4; mi++)
    #pragma unroll
    for (int j=0; j<4; j++){
      int r = m0 + wm*64 + mi*16 + l4*4 + j;
      float4 xv0 = *(const float4*)(xa + (size_t)r*8);
      float4 xv1 = *(const float4*)(xa + (size_t)r*8 + 4);
      #pragma unroll
      for (int ni=0; ni<4; ni++){
        int col = n0 + wn*64 + ni*16 + l15;
        float v = acc[mi][ni][j] + bv[ni] + LORA_SCALE * (
            xv0.x*lb0[ni].x + xv0.y*lb0[ni].y + xv0.z*lb0[ni].z + xv0.w*lb0[ni].w +
            xv1.x*lb1[ni].x + xv1.y*lb1[ni].y + xv1.z*lb1[ni].z + xv1.w*lb1[ni].w);
        v *= oscale;
        if (f32out){
          ((float*)outp)[(size_t)r*Nd + col] = v;
        } else {
          int cs = swz ? (col ^ ((r & 7) << 3)) : col;
          ((u16*)outp)[(size_t)r*Nd + cs] = f2bf(v);
        }
      }
    }
}

// ---------------- V transpose: V[4096][2048] -> Vt[bh][d][s] (kv-swizzled) ----------------
__global__ __launch_bounds__(256) void transpose_v(const u16* __restrict__ V,
                                                   u16* __restrict__ Vt){
  __shared__ u16 tile[64*80];
  int tid = threadIdx.x;
  int f0 = blockIdx.x * 64, m0 = blockIdx.y * 64;
  int i = tid >> 2, j0 = (tid & 3) * 16;
  #pragma unroll
  for (int kk=0; kk<16; kk+=8){
    uint4 u = *(const uint4*)(V + (size_t)(m0 + i)*2048 + f0 + j0 + kk);
    *(uint4*)(tile + i*80 + j0 + kk) = u;
  }
  __syncthreads();
  int j = tid >> 2, i0 = (tid & 3) * 16;
  int b = m0 >> 11, s0 = m0 & 2047;
  int h = f0 >> 7, d = (f0 & 127) + j;
  int c = (d & 7) << 3;
  size_t obase = ((size_t)((b*16 + h)*128 + d)) * 2048 + s0;
  #pragma unroll
  for (int kk=0; kk<16; kk+=8){
    u16 v8[8];
    #pragma unroll
    for (int u2=0; u2<8; ++u2) v8[u2] = tile[(i0+kk+u2)*80 + j];
    *(uint4*)(Vt + obase + ((i0+kk) ^ c)) = *(const uint4*)v8;   // (x^c)+u == (x+u)^c, c%8==0
  }
}

// ---------------- flash attention: QBLK=128, KVBLK=64, 4 waves x 32 q-rows ----------------
__global__ __launch_bounds__(256, 2) void attn_kernel(
    const u16* __restrict__ Q, const u16* __restrict__ K,
    const u16* __restrict__ Vt, u16* __restrict__ ctx){
  __shared__ u16 Qsh[128*128];   // 32 KB
  __shared__ u16 Ksh[64*128];    // 16 KB
  __shared__ u16 Vsh[128*64];    // 16 KB
  __shared__ u16 Psh[4*32*64];   // 16 KB
  int tid = threadIdx.x, w = tid >> 6, lane = tid & 63;
  int l15 = lane & 15, l4 = lane >> 4;
  int qt = blockIdx.x, bh = blockIdx.y;
  int b = bh >> 4, h = bh & 15;
  const u16* Qg = Q + (size_t)(b*2048 + qt*128) * 2048 + h*128;
  const u16* Kg = K + (size_t)(b*2048) * 2048 + h*128;
  const u16* Vg = Vt + (size_t)bh * 128 * 2048;

  #pragma unroll
  for (int i=0; i<8; ++i){
    int e = (i*256 + tid) * 8;
    int r = e >> 7, cc = e & 127;
    gload16(Qg + (size_t)r*2048 + cc, (char*)Qsh + i*4096 + w*1024);
  }
  __syncthreads();
  bf16x8 qf[2][4];                       // Q hoisted to registers (pre-scaled by 1/sqrt(dk))
  #pragma unroll
  for (int mi=0; mi<2; mi++){
    int r = w*32 + mi*16 + l15;
    #pragma unroll
    for (int kb=0; kb<4; kb++){
      int cc = (kb*32 + l4*8) ^ ((r & 7) << 3);
      qf[mi][kb] = *(const bf16x8*)(Qsh + r*128 + cc);
    }
  }
  f32x4 ctxa[2][8];
  #pragma unroll
  for (int mi=0; mi<2; mi++)
    #pragma unroll
    for (int nd=0; nd<8; nd++) ctxa[mi][nd] = (f32x4){0.f,0.f,0.f,0.f};
  float mrun[2][4], lrun[2][4], corr[2][4];
  #pragma unroll
  for (int mi=0; mi<2; mi++)
    #pragma unroll
    for (int j=0; j<4; j++){ mrun[mi][j] = -3.0e38f; lrun[mi][j] = 0.f; }

  u16* Pw = Psh + w * (32*64);

  for (int kv0 = 0; kv0 < 2048; kv0 += 64){
    __syncthreads();
    #pragma unroll
    for (int i=0; i<4; ++i){
      int e = (i*256 + tid) * 8;
      int r = e >> 7, cc = e & 127;
      gload16(Kg + (size_t)(kv0 + r)*2048 + cc, (char*)Ksh + i*4096 + w*1024);
      int dd = e >> 6, c2 = e & 63;
      gload16(Vg + (size_t)dd*2048 + kv0 + c2, (char*)Vsh + i*4096 + w*1024);
    }
    __syncthreads();
    // S = Q K^T   (D[q][kv], col=kv=l15, row=q=l4*4+j)
    f32x4 s[2][4];
    #pragma unroll
    for (int mi=0; mi<2; mi++)
      #pragma unroll
      for (int ni=0; ni<4; ni++) s[mi][ni] = (f32x4){0.f,0.f,0.f,0.f};
    #pragma unroll
    for (int kb=0; kb<4; kb++){
      #pragma unroll
      for (int ni=0; ni<4; ni++){
        int r = ni*16 + l15;
        int cc = (kb*32 + l4*8) ^ ((r & 7) << 3);
        bf16x8 kf = *(const bf16x8*)(Ksh + r*128 + cc);
        #pragma unroll
        for (int mi=0; mi<2; mi++)
          s[mi][ni] = __builtin_amdgcn_mfma_f32_16x16x32_bf16(qf[mi][kb], kf, s[mi][ni], 0, 0, 0);
      }
    }
    // online softmax, wave-parallel row reductions (16-lane groups)
    #pragma unroll
    for (int mi=0; mi<2; mi++){
      #pragma unroll
      for (int j=0; j<4; j++){
        float v = fmaxf(fmaxf(s[mi][0][j], s[mi][1][j]), fmaxf(s[mi][2][j], s[mi][3][j]));
        v = fmaxf(v, __shfl_xor(v, 1));
        v = fmaxf(v, __shfl_xor(v, 2));
        v = fmaxf(v, __shfl_xor(v, 4));
        v = fmaxf(v, __shfl_xor(v, 8));
        float mnew = fmaxf(mrun[mi][j], v);
        float cr = __expf(mrun[mi][j] - mnew);
        int row = mi*16 + l4*4 + j;
        int sw = (row & 7) << 3;
        float ps = 0.f;
        #pragma unroll
        for (int ni=0; ni<4; ni++){
          float p = __expf(s[mi][ni][j] - mnew);
          ps += p;
          Pw[row*64 + ((ni*16 + l15) ^ sw)] = f2bf(p);
        }
        ps += __shfl_xor(ps, 1);
        ps += __shfl_xor(ps, 2);
        ps += __shfl_xor(ps, 4);
        ps += __shfl_xor(ps, 8);
        lrun[mi][j] = lrun[mi][j]*cr + ps;
        mrun[mi][j] = mnew;
        corr[mi][j] = cr;
      }
    }
    #pragma unroll
    for (int mi=0; mi<2; mi++){
      f32x4 cv = (f32x4){corr[mi][0], corr[mi][1], corr[mi][2], corr[mi][3]};
      #pragma unroll
      for (int nd=0; nd<8; nd++) ctxa[mi][nd] *= cv;
    }
    // PV: ctx[q][d] += P[q][kv] * V[kv][d]
    bf16x8 pa[2][2];
    #pragma unroll
    for (int mi=0; mi<2; mi++){
      int r = mi*16 + l15;
      int sw = (r & 7) << 3;
      #pragma unroll
      for (int kvb=0; kvb<2; kvb++)
        pa[mi][kvb] = *(const bf16x8*)(Pw + r*64 + ((kvb*32 + l4*8) ^ sw));
    }
    #pragma unroll
    for (int nd=0; nd<8; nd++){
      int dd = nd*16 + l15;
      int sw = (dd & 7) << 3;
      #pragma unroll
      for (int kvb=0; kvb<2; kvb++){
        bf16x8 vf = *(const bf16x8*)(Vsh + dd*64 + ((kvb*32 + l4*8) ^ sw));
        #pragma unroll
        for (int mi=0; mi<2; mi++)
          ctxa[mi][nd] = __builtin_amdgcn_mfma_f32_16x16x32_bf16(pa[mi][kvb], vf, ctxa[mi][nd], 0, 0, 0);
      }
    }
  }
  // normalize + write context (plain bf16 layout [token][h*128+d])
  #pragma unroll
  for (int mi=0; mi<2; mi++)
    #pragma unroll
    for (int j=0; j<4; j++){
      float inv = 1.0f / lrun[mi][j];
      int srow = qt*128 + w*32 + mi*16 + l4*4 + j;
      size_t base = ((size_t)(b*2048 + srow)) * 2048 + h*128;
      #pragma unroll
      for (int nd=0; nd<8; nd++)
        ctx[base + nd*16 + l15] = f2bf(ctxa[mi][nd][j] * inv);
    }
}

// ---------------- launcher ----------------
extern "C" void kernel_launch(void* const* d_in, const int* in_sizes, int n_in,
                              void* d_out, int out_size, void* d_ws, size_t ws_size,
                              hipStream_t stream){
  const float* x  = (const float*)d_in[0];
  const float* Wq = (const float*)d_in[1];  const float* bq = (const float*)d_in[2];
  const float* Aq = (const float*)d_in[3];  const float* Bq = (const float*)d_in[4];
  const float* Wk = (const float*)d_in[5];  const float* bk = (const float*)d_in[6];
  const float* Ak = (const float*)d_in[7];  const float* Bk = (const float*)d_in[8];
  const float* Wv = (const float*)d_in[9];  const float* bv = (const float*)d_in[10];
  const float* Av = (const float*)d_in[11]; const float* Bv = (const float*)d_in[12];
  const float* Wo = (const float*)d_in[13]; const float* bo = (const float*)d_in[14];
  const float* Ao = (const float*)d_in[15]; const float* Bo = (const float*)d_in[16];

  char* ws = (char*)d_ws;
  size_t off = 0;
  u16* xbf = (u16*)(ws + off); off += (size_t)4096*2048*2;          // 16 MB
  u16* wqb = (u16*)(ws + off); off += (size_t)2048*2048*2;
  u16* wkb = (u16*)(ws + off); off += (size_t)2048*2048*2;
  u16* wvb = (u16*)(ws + off); off += (size_t)2048*2048*2;
  u16* wob = (u16*)(ws + off); off += (size_t)2048*2048*2;          // +32 MB
  float* xa = (float*)(ws + off); off += (size_t)4*32768*4;         // 4 slabs [4096][8]
  u16* Qb  = (u16*)(ws + off); off += (size_t)4096*2048*2;
  u16* Kb  = (u16*)(ws + off); off += (size_t)4096*2048*2;
  u16* Vb  = (u16*)(ws + off); off += (size_t)4096*2048*2;          // later reused as ctx
  u16* Vtb = (u16*)(ws + off); off += (size_t)4096*2048*2;
  if (ws_size < off) return;   // insufficient scratch — bail (will fail validation loudly)

  cvt_f32_bf16<<<4096, 256, 0, stream>>>(x,  xbf, 4096*2048);
  cvt_f32_bf16<<<2048, 256, 0, stream>>>(Wq, wqb, 2048*2048);
  cvt_f32_bf16<<<2048, 256, 0, stream>>>(Wk, wkb, 2048*2048);
  cvt_f32_bf16<<<2048, 256, 0, stream>>>(Wv, wvb, 2048*2048);
  cvt_f32_bf16<<<2048, 256, 0, stream>>>(Wo, wob, 2048*2048);

  lora_xa_kernel<3, 0><<<1024, 256, 0, stream>>>((const void*)x, Aq, Ak, Av, xa);

  // Q (swizzled, pre-scaled), K (swizzled), V (plain)
  gemm_fused<<<dim3(16,32), 256, 0, stream>>>(xbf, wqb, bq, Bq, xa,        Qb, 0, 1, QSCALE);
  gemm_fused<<<dim3(16,32), 256, 0, stream>>>(xbf, wkb, bk, Bk, xa+32768,  Kb, 0, 1, 1.0f);
  gemm_fused<<<dim3(16,32), 256, 0, stream>>>(xbf, wvb, bv, Bv, xa+65536,  Vb, 0, 0, 1.0f);

  transpose_v<<<dim3(32,64), 256, 0, stream>>>(Vb, Vtb);

  attn_kernel<<<dim3(16,32), 256, 0, stream>>>(Qb, Kb, Vtb, Vb);   // ctx -> Vb (V dead after transpose)

  lora_xa_kernel<1, 1><<<1024, 256, 0, stream>>>((const void*)Vb, Ao, Ao, Ao, xa+98304);

  gemm_fused<<<dim3(16,32), 256, 0, stream>>>(Vb, wob, bo, Bo, xa+98304, d_out, 1, 0, 1.0f);
}

// Round 2
// 423.267 us; speedup vs baseline: 1.0505x; 1.0505x over previous
//
#include <hip/hip_runtime.h>
#include <stdint.h>

typedef unsigned short u16;
typedef unsigned int   u32;
typedef __bf16  bf16x8 __attribute__((ext_vector_type(8)));
typedef float   f32x4  __attribute__((ext_vector_type(4)));

#define LORA_SCALE 2.0f
#define QSCALE 0.08838834764831845f   // 1/sqrt(128)
#define LOG2E  1.4426950408889634f

__device__ __forceinline__ u16 f2bf(float f){
  u32 u = __builtin_bit_cast(u32, f);
  u32 r = (u + 0x7fffu + ((u >> 16) & 1u)) >> 16;   // RNE
  return (u16)r;
}
__device__ __forceinline__ float bf2f(u16 v){
  return __builtin_bit_cast(float, ((u32)v) << 16);
}

typedef __attribute__((address_space(3))) u32 lds_u32_t;
typedef __attribute__((address_space(1))) const u32 g_u32_t;

// async global->LDS, 16B per lane; LDS dest = wave-uniform base + lane*16
__device__ __forceinline__ void gload16(const void* g, void* l){
  __builtin_amdgcn_global_load_lds((g_u32_t*)(unsigned long long)g,
                                   (lds_u32_t*)(u32)(unsigned long long)l,
                                   16, 0, 0);
}

// DPP rotate within 16-lane rows (VALU pipe, not LDS pipe)
template<int N>
__device__ __forceinline__ float ror16(float x){
  return __builtin_bit_cast(float,
    __builtin_amdgcn_update_dpp(0, __builtin_bit_cast(int, x),
                                0x120 | N, 0xF, 0xF, false));
}
__device__ __forceinline__ float rowmax16(float v){
  v = fmaxf(v, ror16<8>(v));
  v = fmaxf(v, ror16<4>(v));
  v = fmaxf(v, ror16<2>(v));
  v = fmaxf(v, ror16<1>(v));
  return v;
}
__device__ __forceinline__ float rowsum16(float v){
  v += ror16<8>(v);
  v += ror16<4>(v);
  v += ror16<2>(v);
  v += ror16<1>(v);
  return v;
}

// ---------------- fp32 -> bf16 convert ----------------
__global__ __launch_bounds__(256) void cvt_f32_bf16(const float* __restrict__ in,
                                                    u16* __restrict__ out, int n){
  int i = (blockIdx.x * 256 + threadIdx.x) * 8;
  if (i >= n) return;
  float4 a = *(const float4*)(in + i);
  float4 b = *(const float4*)(in + i + 4);
  u16 o[8] = {f2bf(a.x),f2bf(a.y),f2bf(a.z),f2bf(a.w),
              f2bf(b.x),f2bf(b.y),f2bf(b.z),f2bf(b.w)};
  *(uint4*)(out + i) = *(const uint4*)o;
}

// ---------------- LoRA stage 1: xa[m][r] = sum_k in[m][k]*A_g[r][k] ----------------
template<int NG, int BF16IN>
__global__ __launch_bounds__(256) void lora_xa_kernel(const void* __restrict__ xin,
    const float* __restrict__ A0, const float* __restrict__ A1, const float* __restrict__ A2,
    float* __restrict__ xout){
  int w = threadIdx.x >> 6, lane = threadIdx.x & 63;
  int m = blockIdx.x * 4 + w;
  float acc[NG][8];
  #pragma unroll
  for (int g=0; g<NG; ++g)
    #pragma unroll
    for (int r=0; r<8; ++r) acc[g][r] = 0.f;
  const float* As[3] = {A0, A1, A2};
  #pragma unroll 1
  for (int it=0; it<8; ++it){
    int k = it*256 + lane*4;
    float4 xv;
    if (BF16IN){
      const u16* xp = (const u16*)xin + (size_t)m*2048 + k;
      ushort4 u = *(const ushort4*)xp;
      xv.x = bf2f(u.x); xv.y = bf2f(u.y); xv.z = bf2f(u.z); xv.w = bf2f(u.w);
    } else {
      xv = *(const float4*)((const float*)xin + (size_t)m*2048 + k);
    }
    #pragma unroll
    for (int g=0; g<NG; ++g){
      const float* Ag = As[g];
      #pragma unroll
      for (int r=0; r<8; ++r){
        float4 av = *(const float4*)(Ag + r*2048 + k);
        acc[g][r] += xv.x*av.x + xv.y*av.y + xv.z*av.z + xv.w*av.w;
      }
    }
  }
  #pragma unroll
  for (int g=0; g<NG; ++g)
    #pragma unroll
    for (int r=0; r<8; ++r){
      float v = acc[g][r];
      #pragma unroll
      for (int off=32; off; off>>=1) v += __shfl_xor(v, off);
      if (lane == 0) xout[g*32768 + m*8 + r] = v;
    }
}

// ---------------- fused GEMM: out = A @ W^T + bias + 2*(xa @ lB^T)  ----------------
__global__ __launch_bounds__(256, 2) void gemm_fused(
    const u16* __restrict__ A, const u16* __restrict__ W,
    const float* __restrict__ bias, const float* __restrict__ lB,
    const float* __restrict__ xa, void* __restrict__ outp,
    int f32out, int swz, float oscale){
  const int Kd = 2048, Nd = 2048;
  __shared__ u16 Ash[128*32];
  __shared__ u16 Bsh[128*32];
  int tid = threadIdx.x, w = tid >> 6, lane = tid & 63;
  int l15 = lane & 15, l4 = lane >> 4;
  int n0 = blockIdx.x * 128, m0 = blockIdx.y * 128;
  int wm = w >> 1, wn = w & 1;
  f32x4 acc[4][4];
  #pragma unroll
  for (int mi=0; mi<4; mi++)
    #pragma unroll
    for (int ni=0; ni<4; ni++) acc[mi][ni] = (f32x4){0.f,0.f,0.f,0.f};

  const u16* Arow = A + (size_t)m0 * Kd;
  const u16* Wrow = W + (size_t)n0 * Kd;
  for (int kt = 0; kt < Kd; kt += 32){
    __syncthreads();
    #pragma unroll
    for (int i=0; i<2; ++i){
      int e = (i*256 + tid) * 8;
      int r = e >> 5, c = e & 31;
      gload16(Arow + (size_t)r*Kd + kt + c, (char*)Ash + i*4096 + w*1024);
      gload16(Wrow + (size_t)r*Kd + kt + c, (char*)Bsh + i*4096 + w*1024);
    }
    __syncthreads();
    bf16x8 af[4], bfv[4];
    #pragma unroll
    for (int mi=0; mi<4; mi++)
      af[mi] = *(const bf16x8*)(Ash + (wm*64 + mi*16 + l15)*32 + l4*8);
    #pragma unroll
    for (int ni=0; ni<4; ni++)
      bfv[ni] = *(const bf16x8*)(Bsh + (wn*64 + ni*16 + l15)*32 + l4*8);
    #pragma unroll
    for (int mi=0; mi<4; mi++)
      #pragma unroll
      for (int ni=0; ni<4; ni++)
        acc[mi][ni] = __builtin_amdgcn_mfma_f32_16x16x32_bf16(af[mi], bfv[ni], acc[mi][ni], 0, 0, 0);
  }
  // epilogue: bias + LoRA + optional scale, write fp32 or (swizzled) bf16
  float bv[4]; float4 lb0[4], lb1[4];
  #pragma unroll
  for (int ni=0; ni<4; ni++){
    int col = n0 + wn*64 + ni*16 + l15;
    bv[ni] = bias[col];
    lb0[ni] = *(const float4*)(lB + col*8);
    lb1[ni] = *(const float4*)(lB + col*8 + 4);
  }
  #pragma unroll
  for (int mi=0; mi<4; mi++)
    #pragma unroll
    for (int j=0; j<4; j++){
      int r = m0 + wm*64 + mi*16 + l4*4 + j;
      float4 xv0 = *(const float4*)(xa + (size_t)r*8);
      float4 xv1 = *(const float4*)(xa + (size_t)r*8 + 4);
      #pragma unroll
      for (int ni=0; ni<4; ni++){
        int col = n0 + wn*64 + ni*16 + l15;
        float v = acc[mi][ni][j] + bv[ni] + LORA_SCALE * (
            xv0.x*lb0[ni].x + xv0.y*lb0[ni].y + xv0.z*lb0[ni].z + xv0.w*lb0[ni].w +
            xv1.x*lb1[ni].x + xv1.y*lb1[ni].y + xv1.z*lb1[ni].z + xv1.w*lb1[ni].w);
        v *= oscale;
        if (f32out){
          ((float*)outp)[(size_t)r*Nd + col] = v;
        } else {
          int cs = swz ? (col ^ ((r & 7) << 3)) : col;
          ((u16*)outp)[(size_t)r*Nd + cs] = f2bf(v);
        }
      }
    }
}

// ---------------- V transpose: V[4096][2048] -> Vt[bh][d][s] (kv-swizzled) ----------------
__global__ __launch_bounds__(256) void transpose_v(const u16* __restrict__ V,
                                                   u16* __restrict__ Vt){
  __shared__ u16 tile[64*80];
  int tid = threadIdx.x;
  int f0 = blockIdx.x * 64, m0 = blockIdx.y * 64;
  int i = tid >> 2, j0 = (tid & 3) * 16;
  #pragma unroll
  for (int kk=0; kk<16; kk+=8){
    uint4 u = *(const uint4*)(V + (size_t)(m0 + i)*2048 + f0 + j0 + kk);
    *(uint4*)(tile + i*80 + j0 + kk) = u;
  }
  __syncthreads();
  int j = tid >> 2, i0 = (tid & 3) * 16;
  int b = m0 >> 11, s0 = m0 & 2047;
  int h = f0 >> 7, d = (f0 & 127) + j;
  int c = (d & 7) << 3;
  size_t obase = ((size_t)((b*16 + h)*128 + d)) * 2048 + s0;
  #pragma unroll
  for (int kk=0; kk<16; kk+=8){
    u16 v8[8];
    #pragma unroll
    for (int u2=0; u2<8; ++u2) v8[u2] = tile[(i0+kk+u2)*80 + j];
    *(uint4*)(Vt + obase + ((i0+kk) ^ c)) = *(const uint4*)v8;   // (x^c)+u == (x+u)^c, c%8==0
  }
}

// ---------------- flash attention: QBLK=128, KVBLK=64, 4 waves x 32 q-rows ----------------
// Double-buffered K/V (Q's LDS reused as 2nd buffer); DPP softmax reductions;
// exp2-domain scores (Q pre-scaled by log2e/sqrt(dk)); setprio around MFMA.
__global__ __launch_bounds__(256, 2) void attn_kernel(
    const u16* __restrict__ Q, const u16* __restrict__ K,
    const u16* __restrict__ Vt, u16* __restrict__ ctx){
  __shared__ u16 buf[2][16384];  // per buffer: K [64][128] (8192 u16) then V [128][64]
  __shared__ u16 Psh[4*32*64];   // 16 KB
  int tid = threadIdx.x, w = tid >> 6, lane = tid & 63;
  int l15 = lane & 15, l4 = lane >> 4;
  int qt = blockIdx.x, bh = blockIdx.y;
  int b = bh >> 4, h = bh & 15;
  const u16* Qg = Q + (size_t)(b*2048 + qt*128) * 2048 + h*128;
  const u16* Kg = K + (size_t)(b*2048) * 2048 + h*128;
  const u16* Vg = Vt + (size_t)bh * 128 * 2048;

  // prologue: Q -> buf[1], kv-tile 0 -> buf[0]
  #pragma unroll
  for (int i=0; i<8; ++i){
    int e = (i*256 + tid) * 8;
    int r = e >> 7, cc = e & 127;
    gload16(Qg + (size_t)r*2048 + cc, (char*)buf[1] + i*4096 + w*1024);
  }
  #pragma unroll
  for (int i=0; i<4; ++i){
    int e = (i*256 + tid) * 8;
    int r = e >> 7, cc = e & 127;
    gload16(Kg + (size_t)r*2048 + cc, (char*)buf[0] + i*4096 + w*1024);
    int dd = e >> 6, c2 = e & 63;
    gload16(Vg + (size_t)dd*2048 + c2, (char*)buf[0] + 16384 + i*4096 + w*1024);
  }
  __syncthreads();   // drains vmcnt

  bf16x8 qf[2][4];   // Q in registers (pre-scaled by log2e/sqrt(dk))
  #pragma unroll
  for (int mi=0; mi<2; mi++){
    int r = w*32 + mi*16 + l15;
    #pragma unroll
    for (int kb=0; kb<4; kb++){
      int cc = (kb*32 + l4*8) ^ ((r & 7) << 3);
      qf[mi][kb] = *(const bf16x8*)(buf[1] + r*128 + cc);
    }
  }
  __syncthreads();   // all waves done with Q region before it becomes buffer 1

  f32x4 ctxa[2][8];
  #pragma unroll
  for (int mi=0; mi<2; mi++)
    #pragma unroll
    for (int nd=0; nd<8; nd++) ctxa[mi][nd] = (f32x4){0.f,0.f,0.f,0.f};
  float mrun[2][4], lrun[2][4], corr[2][4];
  #pragma unroll
  for (int mi=0; mi<2; mi++)
    #pragma unroll
    for (int j=0; j<4; j++){ mrun[mi][j] = -3.0e38f; lrun[mi][j] = 0.f; }

  u16* Pw = Psh + w * (32*64);

  for (int t = 0; t < 32; ++t){
    int cur = t & 1;
    const u16* Kc = buf[cur];
    const u16* Vc = buf[cur] + 8192;
    // prefetch next kv tile into the other buffer (latency hides under compute)
    if (t + 1 < 32){
      int kvn = (t + 1) * 64;
      char* bn = (char*)buf[cur ^ 1];
      #pragma unroll
      for (int i=0; i<4; ++i){
        int e = (i*256 + tid) * 8;
        int r = e >> 7, cc = e & 127;
        gload16(Kg + (size_t)(kvn + r)*2048 + cc, bn + i*4096 + w*1024);
        int dd = e >> 6, c2 = e & 63;
        gload16(Vg + (size_t)dd*2048 + kvn + c2, bn + 16384 + i*4096 + w*1024);
      }
    }
    // S = Q K^T   (D[q][kv], col=kv=l15, row=q=l4*4+j)
    f32x4 s[2][4];
    #pragma unroll
    for (int mi=0; mi<2; mi++)
      #pragma unroll
      for (int ni=0; ni<4; ni++) s[mi][ni] = (f32x4){0.f,0.f,0.f,0.f};
    __builtin_amdgcn_s_setprio(1);
    #pragma unroll
    for (int kb=0; kb<4; kb++){
      #pragma unroll
      for (int ni=0; ni<4; ni++){
        int r = ni*16 + l15;
        int cc = (kb*32 + l4*8) ^ ((r & 7) << 3);
        bf16x8 kf = *(const bf16x8*)(Kc + r*128 + cc);
        #pragma unroll
        for (int mi=0; mi<2; mi++)
          s[mi][ni] = __builtin_amdgcn_mfma_f32_16x16x32_bf16(qf[mi][kb], kf, s[mi][ni], 0, 0, 0);
      }
    }
    __builtin_amdgcn_s_setprio(0);
    // online softmax in exp2 domain; DPP row reductions (VALU pipe)
    #pragma unroll
    for (int mi=0; mi<2; mi++){
      #pragma unroll
      for (int j=0; j<4; j++){
        float v = fmaxf(fmaxf(s[mi][0][j], s[mi][1][j]), fmaxf(s[mi][2][j], s[mi][3][j]));
        v = rowmax16(v);
        float mnew = fmaxf(mrun[mi][j], v);
        float cr = exp2f(mrun[mi][j] - mnew);
        int row = mi*16 + l4*4 + j;
        int sw = (row & 7) << 3;
        float ps = 0.f;
        #pragma unroll
        for (int ni=0; ni<4; ni++){
          float p = exp2f(s[mi][ni][j] - mnew);
          ps += p;
          Pw[row*64 + ((ni*16 + l15) ^ sw)] = f2bf(p);
        }
        ps = rowsum16(ps);
        lrun[mi][j] = lrun[mi][j]*cr + ps;
        mrun[mi][j] = mnew;
        corr[mi][j] = cr;
      }
    }
    #pragma unroll
    for (int mi=0; mi<2; mi++){
      f32x4 cv = (f32x4){corr[mi][0], corr[mi][1], corr[mi][2], corr[mi][3]};
      #pragma unroll
      for (int nd=0; nd<8; nd++) ctxa[mi][nd] *= cv;
    }
    // PV: ctx[q][d] += P[q][kv] * V[kv][d]
    bf16x8 pa[2][2];
    #pragma unroll
    for (int mi=0; mi<2; mi++){
      int r = mi*16 + l15;
      int sw = (r & 7) << 3;
      #pragma unroll
      for (int kvb=0; kvb<2; kvb++)
        pa[mi][kvb] = *(const bf16x8*)(Pw + r*64 + ((kvb*32 + l4*8) ^ sw));
    }
    __builtin_amdgcn_s_setprio(1);
    #pragma unroll
    for (int nd=0; nd<8; nd++){
      int dd = nd*16 + l15;
      int sw = (dd & 7) << 3;
      #pragma unroll
      for (int kvb=0; kvb<2; kvb++){
        bf16x8 vf = *(const bf16x8*)(Vc + dd*64 + ((kvb*32 + l4*8) ^ sw));
        #pragma unroll
        for (int mi=0; mi<2; mi++)
          ctxa[mi][nd] = __builtin_amdgcn_mfma_f32_16x16x32_bf16(pa[mi][kvb], vf, ctxa[mi][nd], 0, 0, 0);
      }
    }
    __builtin_amdgcn_s_setprio(0);
    __syncthreads();   // implicit vmcnt(0): next buffer ready; all waves done with cur
  }
  // normalize + write context (plain bf16 layout [token][h*128+d])
  #pragma unroll
  for (int mi=0; mi<2; mi++)
    #pragma unroll
    for (int j=0; j<4; j++){
      float inv = 1.0f / lrun[mi][j];
      int srow = qt*128 + w*32 + mi*16 + l4*4 + j;
      size_t base = ((size_t)(b*2048 + srow)) * 2048 + h*128;
      #pragma unroll
      for (int nd=0; nd<8; nd++)
        ctx[base + nd*16 + l15] = f2bf(ctxa[mi][nd][j] * inv);
    }
}

// ---------------- launcher ----------------
extern "C" void kernel_launch(void* const* d_in, const int* in_sizes, int n_in,
                              void* d_out, int out_size, void* d_ws, size_t ws_size,
                              hipStream_t stream){
  const float* x  = (const float*)d_in[0];
  const float* Wq = (const float*)d_in[1];  const float* bq = (const float*)d_in[2];
  const float* Aq = (const float*)d_in[3];  const float* Bq = (const float*)d_in[4];
  const float* Wk = (const float*)d_in[5];  const float* bk = (const float*)d_in[6];
  const float* Ak = (const float*)d_in[7];  const float* Bk = (const float*)d_in[8];
  const float* Wv = (const float*)d_in[9];  const float* bv = (const float*)d_in[10];
  const float* Av = (const float*)d_in[11]; const float* Bv = (const float*)d_in[12];
  const float* Wo = (const float*)d_in[13]; const float* bo = (const float*)d_in[14];
  const float* Ao = (const float*)d_in[15]; const float* Bo = (const float*)d_in[16];

  char* ws = (char*)d_ws;
  size_t off = 0;
  u16* xbf = (u16*)(ws + off); off += (size_t)4096*2048*2;          // 16 MB
  u16* wqb = (u16*)(ws + off); off += (size_t)2048*2048*2;
  u16* wkb = (u16*)(ws + off); off += (size_t)2048*2048*2;
  u16* wvb = (u16*)(ws + off); off += (size_t)2048*2048*2;
  u16* wob = (u16*)(ws + off); off += (size_t)2048*2048*2;          // +32 MB
  float* xa = (float*)(ws + off); off += (size_t)4*32768*4;         // 4 slabs [4096][8]
  u16* Qb  = (u16*)(ws + off); off += (size_t)4096*2048*2;
  u16* Kb  = (u16*)(ws + off); off += (size_t)4096*2048*2;
  u16* Vb  = (u16*)(ws + off); off += (size_t)4096*2048*2;          // later reused as ctx
  u16* Vtb = (u16*)(ws + off); off += (size_t)4096*2048*2;
  if (ws_size < off) return;   // insufficient scratch — bail (will fail validation loudly)

  cvt_f32_bf16<<<4096, 256, 0, stream>>>(x,  xbf, 4096*2048);
  cvt_f32_bf16<<<2048, 256, 0, stream>>>(Wq, wqb, 2048*2048);
  cvt_f32_bf16<<<2048, 256, 0, stream>>>(Wk, wkb, 2048*2048);
  cvt_f32_bf16<<<2048, 256, 0, stream>>>(Wv, wvb, 2048*2048);
  cvt_f32_bf16<<<2048, 256, 0, stream>>>(Wo, wob, 2048*2048);

  lora_xa_kernel<3, 0><<<1024, 256, 0, stream>>>((const void*)x, Aq, Ak, Av, xa);

  // Q (swizzled, pre-scaled into exp2 domain), K (swizzled), V (plain)
  gemm_fused<<<dim3(16,32), 256, 0, stream>>>(xbf, wqb, bq, Bq, xa,        Qb, 0, 1, QSCALE*LOG2E);
  gemm_fused<<<dim3(16,32), 256, 0, stream>>>(xbf, wkb, bk, Bk, xa+32768,  Kb, 0, 1, 1.0f);
  gemm_fused<<<dim3(16,32), 256, 0, stream>>>(xbf, wvb, bv, Bv, xa+65536,  Vb, 0, 0, 1.0f);

  transpose_v<<<dim3(32,64), 256, 0, stream>>>(Vb, Vtb);

  attn_kernel<<<dim3(16,32), 256, 0, stream>>>(Qb, Kb, Vtb, Vb);   // ctx -> Vb (V dead after transpose)

  lora_xa_kernel<1, 1><<<1024, 256, 0, stream>>>((const void*)Vb, Ao, Ao, Ao, xa+98304);

  gemm_fused<<<dim3(16,32), 256, 0, stream>>>(Vb, wob, bo, Bo, xa+98304, d_out, 1, 0, 1.0f);
}

// Round 3
// 391.678 us; speedup vs baseline: 1.1352x; 1.0806x over previous
//
#include <hip/hip_runtime.h>
#include <stdint.h>

typedef unsigned short u16;
typedef unsigned int   u32;
typedef __bf16  bf16x8 __attribute__((ext_vector_type(8)));
typedef float   f32x4  __attribute__((ext_vector_type(4)));

#define LORA_SCALE 2.0f
#define QSCALE 0.08838834764831845f   // 1/sqrt(128)
#define LOG2E  1.4426950408889634f
#define RESCALE_THR 8.0f

__device__ __forceinline__ u16 f2bf(float f){
  u32 u = __builtin_bit_cast(u32, f);
  u32 r = (u + 0x7fffu + ((u >> 16) & 1u)) >> 16;   // RNE
  return (u16)r;
}
__device__ __forceinline__ float bf2f(u16 v){
  return __builtin_bit_cast(float, ((u32)v) << 16);
}
// pack 2 f32 -> 2 bf16 in one VALU op (no builtin on gfx950; T12 recipe)
__device__ __forceinline__ u32 cvt_pk_bf16(float lo, float hi){
  u32 d;
  asm("v_cvt_pk_bf16_f32 %0, %1, %2" : "=v"(d) : "v"(lo), "v"(hi));
  return d;
}

typedef __attribute__((address_space(3))) u32 lds_u32_t;
typedef __attribute__((address_space(1))) const u32 g_u32_t;

// async global->LDS, 16B per lane; LDS dest = wave-uniform base + lane*16
__device__ __forceinline__ void gload16(const void* g, void* l){
  __builtin_amdgcn_global_load_lds((g_u32_t*)(unsigned long long)g,
                                   (lds_u32_t*)(u32)(unsigned long long)l,
                                   16, 0, 0);
}

// ---------------- fp32 -> bf16 convert ----------------
__global__ __launch_bounds__(256) void cvt_f32_bf16(const float* __restrict__ in,
                                                    u16* __restrict__ out, int n){
  int i = (blockIdx.x * 256 + threadIdx.x) * 8;
  if (i >= n) return;
  float4 a = *(const float4*)(in + i);
  float4 b = *(const float4*)(in + i + 4);
  u16 o[8] = {f2bf(a.x),f2bf(a.y),f2bf(a.z),f2bf(a.w),
              f2bf(b.x),f2bf(b.y),f2bf(b.z),f2bf(b.w)};
  *(uint4*)(out + i) = *(const uint4*)o;
}

// ---------------- LoRA stage 1: xa[m][r] = sum_k in[m][k]*A_g[r][k] ----------------
template<int NG, int BF16IN>
__global__ __launch_bounds__(256) void lora_xa_kernel(const void* __restrict__ xin,
    const float* __restrict__ A0, const float* __restrict__ A1, const float* __restrict__ A2,
    float* __restrict__ xout){
  int w = threadIdx.x >> 6, lane = threadIdx.x & 63;
  int m = blockIdx.x * 4 + w;
  float acc[NG][8];
  #pragma unroll
  for (int g=0; g<NG; ++g)
    #pragma unroll
    for (int r=0; r<8; ++r) acc[g][r] = 0.f;
  const float* As[3] = {A0, A1, A2};
  #pragma unroll 1
  for (int it=0; it<8; ++it){
    int k = it*256 + lane*4;
    float4 xv;
    if (BF16IN){
      const u16* xp = (const u16*)xin + (size_t)m*2048 + k;
      ushort4 u = *(const ushort4*)xp;
      xv.x = bf2f(u.x); xv.y = bf2f(u.y); xv.z = bf2f(u.z); xv.w = bf2f(u.w);
    } else {
      xv = *(const float4*)((const float*)xin + (size_t)m*2048 + k);
    }
    #pragma unroll
    for (int g=0; g<NG; ++g){
      const float* Ag = As[g];
      #pragma unroll
      for (int r=0; r<8; ++r){
        float4 av = *(const float4*)(Ag + r*2048 + k);
        acc[g][r] += xv.x*av.x + xv.y*av.y + xv.z*av.z + xv.w*av.w;
      }
    }
  }
  #pragma unroll
  for (int g=0; g<NG; ++g)
    #pragma unroll
    for (int r=0; r<8; ++r){
      float v = acc[g][r];
      #pragma unroll
      for (int off=32; off; off>>=1) v += __shfl_xor(v, off);
      if (lane == 0) xout[g*32768 + m*8 + r] = v;
    }
}

// ---------------- fused GEMM: out = A @ W^T + bias + 2*(xa @ lB^T)  ----------------
__global__ __launch_bounds__(256, 2) void gemm_fused(
    const u16* __restrict__ A, const u16* __restrict__ W,
    const float* __restrict__ bias, const float* __restrict__ lB,
    const float* __restrict__ xa, void* __restrict__ outp,
    int f32out, int swz, float oscale){
  const int Kd = 2048, Nd = 2048;
  __shared__ u16 Ash[128*32];
  __shared__ u16 Bsh[128*32];
  int tid = threadIdx.x, w = tid >> 6, lane = tid & 63;
  int l15 = lane & 15, l4 = lane >> 4;
  int n0 = blockIdx.x * 128, m0 = blockIdx.y * 128;
  int wm = w >> 1, wn = w & 1;
  f32x4 acc[4][4];
  #pragma unroll
  for (int mi=0; mi<4; mi++)
    #pragma unroll
    for (int ni=0; ni<4; ni++) acc[mi][ni] = (f32x4){0.f,0.f,0.f,0.f};

  const u16* Arow = A + (size_t)m0 * Kd;
  const u16* Wrow = W + (size_t)n0 * Kd;
  for (int kt = 0; kt < Kd; kt += 32){
    __syncthreads();
    #pragma unroll
    for (int i=0; i<2; ++i){
      int e = (i*256 + tid) * 8;
      int r = e >> 5, c = e & 31;
      gload16(Arow + (size_t)r*Kd + kt + c, (char*)Ash + i*4096 + w*1024);
      gload16(Wrow + (size_t)r*Kd + kt + c, (char*)Bsh + i*4096 + w*1024);
    }
    __syncthreads();
    bf16x8 af[4], bfv[4];
    #pragma unroll
    for (int mi=0; mi<4; mi++)
      af[mi] = *(const bf16x8*)(Ash + (wm*64 + mi*16 + l15)*32 + l4*8);
    #pragma unroll
    for (int ni=0; ni<4; ni++)
      bfv[ni] = *(const bf16x8*)(Bsh + (wn*64 + ni*16 + l15)*32 + l4*8);
    #pragma unroll
    for (int mi=0; mi<4; mi++)
      #pragma unroll
      for (int ni=0; ni<4; ni++)
        acc[mi][ni] = __builtin_amdgcn_mfma_f32_16x16x32_bf16(af[mi], bfv[ni], acc[mi][ni], 0, 0, 0);
  }
  // epilogue: bias + LoRA + optional scale, write fp32 or (swizzled) bf16
  float bv[4]; float4 lb0[4], lb1[4];
  #pragma unroll
  for (int ni=0; ni<4; ni++){
    int col = n0 + wn*64 + ni*16 + l15;
    bv[ni] = bias[col];
    lb0[ni] = *(const float4*)(lB + col*8);
    lb1[ni] = *(const float4*)(lB + col*8 + 4);
  }
  #pragma unroll
  for (int mi=0; mi<4; mi++)
    #pragma unroll
    for (int j=0; j<4; j++){
      int r = m0 + wm*64 + mi*16 + l4*4 + j;
      float4 xv0 = *(const float4*)(xa + (size_t)r*8);
      float4 xv1 = *(const float4*)(xa + (size_t)r*8 + 4);
      #pragma unroll
      for (int ni=0; ni<4; ni++){
        int col = n0 + wn*64 + ni*16 + l15;
        float v = acc[mi][ni][j] + bv[ni] + LORA_SCALE * (
            xv0.x*lb0[ni].x + xv0.y*lb0[ni].y + xv0.z*lb0[ni].z + xv0.w*lb0[ni].w +
            xv1.x*lb1[ni].x + xv1.y*lb1[ni].y + xv1.z*lb1[ni].z + xv1.w*lb1[ni].w);
        v *= oscale;
        if (f32out){
          ((float*)outp)[(size_t)r*Nd + col] = v;
        } else {
          int cs = swz ? (col ^ ((r & 7) << 3)) : col;
          ((u16*)outp)[(size_t)r*Nd + cs] = f2bf(v);
        }
      }
    }
}

// ---------------- V transpose: V[4096][2048] -> Vt[bh][d][s] (kv-swizzled) ----------------
__global__ __launch_bounds__(256) void transpose_v(const u16* __restrict__ V,
                                                   u16* __restrict__ Vt){
  __shared__ u16 tile[64*80];
  int tid = threadIdx.x;
  int f0 = blockIdx.x * 64, m0 = blockIdx.y * 64;
  int i = tid >> 2, j0 = (tid & 3) * 16;
  #pragma unroll
  for (int kk=0; kk<16; kk+=8){
    uint4 u = *(const uint4*)(V + (size_t)(m0 + i)*2048 + f0 + j0 + kk);
    *(uint4*)(tile + i*80 + j0 + kk) = u;
  }
  __syncthreads();
  int j = tid >> 2, i0 = (tid & 3) * 16;
  int b = m0 >> 11, s0 = m0 & 2047;
  int h = f0 >> 7, d = (f0 & 127) + j;
  int c = (d & 7) << 3;
  size_t obase = ((size_t)((b*16 + h)*128 + d)) * 2048 + s0;
  #pragma unroll
  for (int kk=0; kk<16; kk+=8){
    u16 v8[8];
    #pragma unroll
    for (int u2=0; u2<8; ++u2) v8[u2] = tile[(i0+kk+u2)*80 + j];
    *(uint4*)(Vt + obase + ((i0+kk) ^ c)) = *(const uint4*)v8;   // (x^c)+u == (x+u)^c, c%8==0
  }
}

// ---------------- flash attention: QBLK=128, KVBLK=64, 4 waves x 32 q-rows ----------------
// Swapped-operand structure (T12 prereq): S^T = mfma(K,Q) -> lane owns q-col l15,
// in-lane softmax; P -> LDS via cvt_pk + ds_write_b64; O^T = mfma(V^T,P) -> rescale
// per-lane; T13 defer-max; coalesced epilogue via LDS transpose.
__global__ __launch_bounds__(256, 2) void attn_kernel(
    const u16* __restrict__ Q, const u16* __restrict__ K,
    const u16* __restrict__ Vt, u16* __restrict__ ctx){
  __shared__ u16 buf[2][16384];  // per buffer: K [64][128] (8192 u16) then V [128][64]
  __shared__ u16 Psh[4*32*64];   // 16 KB: per-wave P [32 q][64 kv], XOR-swizzled
  int tid = threadIdx.x, w = tid >> 6, lane = tid & 63;
  int l15 = lane & 15, l4 = lane >> 4;
  int qt = blockIdx.x, bh = blockIdx.y;
  int b = bh >> 4, h = bh & 15;
  const u16* Qg = Q + (size_t)(b*2048 + qt*128) * 2048 + h*128;
  const u16* Kg = K + (size_t)(b*2048) * 2048 + h*128;
  const u16* Vg = Vt + (size_t)bh * 128 * 2048;

  // prologue: Q -> buf[1], kv-tile 0 -> buf[0]
  #pragma unroll
  for (int i=0; i<8; ++i){
    int e = (i*256 + tid) * 8;
    int r = e >> 7, cc = e & 127;
    gload16(Qg + (size_t)r*2048 + cc, (char*)buf[1] + i*4096 + w*1024);
  }
  #pragma unroll
  for (int i=0; i<4; ++i){
    int e = (i*256 + tid) * 8;
    int r = e >> 7, cc = e & 127;
    gload16(Kg + (size_t)r*2048 + cc, (char*)buf[0] + i*4096 + w*1024);
    int dd = e >> 6, c2 = e & 63;
    gload16(Vg + (size_t)dd*2048 + c2, (char*)buf[0] + 16384 + i*4096 + w*1024);
  }
  __syncthreads();   // drains vmcnt

  bf16x8 qf[2][4];   // Q rows (pre-scaled by log2e/sqrt(dk)); used as B operand
  #pragma unroll
  for (int mi=0; mi<2; mi++){
    int r = w*32 + mi*16 + l15;
    #pragma unroll
    for (int kb=0; kb<4; kb++){
      int cc = (kb*32 + l4*8) ^ ((r & 7) << 3);
      qf[mi][kb] = *(const bf16x8*)(buf[1] + r*128 + cc);
    }
  }
  __syncthreads();   // all waves done with Q region before it becomes buffer 1

  // O^T accumulator: ctxa[mi][nd] reg j -> d = nd*16 + l4*4 + j, q = mi*16 + l15
  f32x4 ctxa[2][8];
  #pragma unroll
  for (int mi=0; mi<2; mi++)
    #pragma unroll
    for (int nd=0; nd<8; nd++) ctxa[mi][nd] = (f32x4){0.f,0.f,0.f,0.f};
  float mrun[2] = {-3.0e38f, -3.0e38f};
  float lrun[2] = {0.f, 0.f};

  char* PwB = (char*)(Psh + w * (32*64));   // byte base of this wave's P tile
  int psw = (l15 & 7) << 4;                 // byte XOR swizzle for P (row = mi*16+l15)

  for (int t = 0; t < 32; ++t){
    int cur = t & 1;
    const u16* Kc = buf[cur];
    const u16* Vc = buf[cur] + 8192;
    // prefetch next kv tile into the other buffer (latency hides under compute)
    if (t + 1 < 32){
      int kvn = (t + 1) * 64;
      char* bn = (char*)buf[cur ^ 1];
      #pragma unroll
      for (int i=0; i<4; ++i){
        int e = (i*256 + tid) * 8;
        int r = e >> 7, cc = e & 127;
        gload16(Kg + (size_t)(kvn + r)*2048 + cc, bn + i*4096 + w*1024);
        int dd = e >> 6, c2 = e & 63;
        gload16(Vg + (size_t)dd*2048 + kvn + c2, bn + 16384 + i*4096 + w*1024);
      }
    }
    // S^T = mfma(K, Q): lane reg j of s[mi][ni]: kv = ni*16 + l4*4 + j, q = mi*16 + l15
    f32x4 s[2][4];
    #pragma unroll
    for (int mi=0; mi<2; mi++)
      #pragma unroll
      for (int ni=0; ni<4; ni++) s[mi][ni] = (f32x4){0.f,0.f,0.f,0.f};
    __builtin_amdgcn_s_setprio(1);
    #pragma unroll
    for (int kb=0; kb<4; kb++){
      #pragma unroll
      for (int ni=0; ni<4; ni++){
        int r = ni*16 + l15;
        int cc = (kb*32 + l4*8) ^ ((r & 7) << 3);
        bf16x8 kf = *(const bf16x8*)(Kc + r*128 + cc);
        s[0][ni] = __builtin_amdgcn_mfma_f32_16x16x32_bf16(kf, qf[0][kb], s[0][ni], 0, 0, 0);
        s[1][ni] = __builtin_amdgcn_mfma_f32_16x16x32_bf16(kf, qf[1][kb], s[1][ni], 0, 0, 0);
      }
    }
    __builtin_amdgcn_s_setprio(0);
    // in-lane tile max per q-row (16 values) + cross-l4 combine
    float pm[2];
    #pragma unroll
    for (int mi=0; mi<2; mi++){
      float v = s[mi][0][0];
      #pragma unroll
      for (int ni=0; ni<4; ni++)
        #pragma unroll
        for (int j=0; j<4; j++) v = fmaxf(v, s[mi][ni][j]);
      v = fmaxf(v, __shfl_xor(v, 16));
      v = fmaxf(v, __shfl_xor(v, 32));
      pm[mi] = v;
    }
    // T13 defer-max: rescale only when max grows beyond THR (exp2 domain)
    bool need = (pm[0] > mrun[0] + RESCALE_THR) || (pm[1] > mrun[1] + RESCALE_THR);
    if (__any(need)){
      #pragma unroll
      for (int mi=0; mi<2; mi++){
        float mnew = fmaxf(mrun[mi], pm[mi]);
        float cr = exp2f(mrun[mi] - mnew);
        lrun[mi] *= cr;
        mrun[mi] = mnew;
        #pragma unroll
        for (int nd=0; nd<8; nd++) ctxa[mi][nd] *= cr;
      }
    }
    // P = exp2(S - m), pack to bf16, ds_write_b64 (4 consecutive kv per write)
    #pragma unroll
    for (int mi=0; mi<2; mi++){
      float ps = 0.f;
      #pragma unroll
      for (int ni=0; ni<4; ni++){
        float p0 = exp2f(s[mi][ni][0] - mrun[mi]);
        float p1 = exp2f(s[mi][ni][1] - mrun[mi]);
        float p2 = exp2f(s[mi][ni][2] - mrun[mi]);
        float p3 = exp2f(s[mi][ni][3] - mrun[mi]);
        ps += (p0 + p1) + (p2 + p3);
        uint2 pk = {cvt_pk_bf16(p0, p1), cvt_pk_bf16(p2, p3)};
        *(uint2*)(PwB + (mi*16 + l15)*128 + ((ni*32 + l4*8) ^ psw)) = pk;
      }
      ps += __shfl_xor(ps, 16);
      ps += __shfl_xor(ps, 32);
      lrun[mi] += ps;
    }
    // PV (swapped): O^T += mfma(V^T, P); B-frag = P[q=l15(+16mi)][kv=l4*8..+8]
    bf16x8 pb[2][2];
    #pragma unroll
    for (int mi=0; mi<2; mi++)
      #pragma unroll
      for (int kvb=0; kvb<2; kvb++)
        pb[mi][kvb] = *(const bf16x8*)(PwB + (mi*16 + l15)*128 + ((kvb*64 + l4*16) ^ psw));
    __builtin_amdgcn_s_setprio(1);
    #pragma unroll
    for (int nd=0; nd<8; nd++){
      int dd = nd*16 + l15;
      int sw = (dd & 7) << 3;
      #pragma unroll
      for (int kvb=0; kvb<2; kvb++){
        bf16x8 vf = *(const bf16x8*)(Vc + dd*64 + ((kvb*32 + l4*8) ^ sw));
        ctxa[0][nd] = __builtin_amdgcn_mfma_f32_16x16x32_bf16(vf, pb[0][kvb], ctxa[0][nd], 0, 0, 0);
        ctxa[1][nd] = __builtin_amdgcn_mfma_f32_16x16x32_bf16(vf, pb[1][kvb], ctxa[1][nd], 0, 0, 0);
      }
    }
    __builtin_amdgcn_s_setprio(0);
    __syncthreads();   // implicit vmcnt(0): next buffer ready; all waves done with cur
  }
  // epilogue: normalize, transpose through per-wave LDS region, coalesced store
  char* OwB = (char*)buf[0] + w*8192;   // [32 q][128 d] bf16, XOR-swizzled
  #pragma unroll
  for (int mi=0; mi<2; mi++){
    float inv = 1.0f / lrun[mi];
    #pragma unroll
    for (int nd=0; nd<8; nd++){
      f32x4 c = ctxa[mi][nd] * inv;
      uint2 pk = {cvt_pk_bf16(c[0], c[1]), cvt_pk_bf16(c[2], c[3])};
      *(uint2*)(OwB + (mi*16 + l15)*256 + ((nd*32 + l4*8) ^ psw)) = pk;
    }
  }
  #pragma unroll
  for (int i=0; i<8; ++i){
    int row = i*4 + l4;          // 0..31
    int colb = l15*16;           // byte col 0..240
    uint4 v = *(const uint4*)(OwB + row*256 + (colb ^ ((row & 7) << 4)));
    int srow = qt*128 + w*32 + row;
    *(uint4*)(ctx + ((size_t)(b*2048 + srow))*2048 + h*128 + colb/2) = v;
  }
}

// ---------------- launcher ----------------
extern "C" void kernel_launch(void* const* d_in, const int* in_sizes, int n_in,
                              void* d_out, int out_size, void* d_ws, size_t ws_size,
                              hipStream_t stream){
  const float* x  = (const float*)d_in[0];
  const float* Wq = (const float*)d_in[1];  const float* bq = (const float*)d_in[2];
  const float* Aq = (const float*)d_in[3];  const float* Bq = (const float*)d_in[4];
  const float* Wk = (const float*)d_in[5];  const float* bk = (const float*)d_in[6];
  const float* Ak = (const float*)d_in[7];  const float* Bk = (const float*)d_in[8];
  const float* Wv = (const float*)d_in[9];  const float* bv = (const float*)d_in[10];
  const float* Av = (const float*)d_in[11]; const float* Bv = (const float*)d_in[12];
  const float* Wo = (const float*)d_in[13]; const float* bo = (const float*)d_in[14];
  const float* Ao = (const float*)d_in[15]; const float* Bo = (const float*)d_in[16];

  char* ws = (char*)d_ws;
  size_t off = 0;
  u16* xbf = (u16*)(ws + off); off += (size_t)4096*2048*2;          // 16 MB
  u16* wqb = (u16*)(ws + off); off += (size_t)2048*2048*2;
  u16* wkb = (u16*)(ws + off); off += (size_t)2048*2048*2;
  u16* wvb = (u16*)(ws + off); off += (size_t)2048*2048*2;
  u16* wob = (u16*)(ws + off); off += (size_t)2048*2048*2;          // +32 MB
  float* xa = (float*)(ws + off); off += (size_t)4*32768*4;         // 4 slabs [4096][8]
  u16* Qb  = (u16*)(ws + off); off += (size_t)4096*2048*2;
  u16* Kb  = (u16*)(ws + off); off += (size_t)4096*2048*2;
  u16* Vb  = (u16*)(ws + off); off += (size_t)4096*2048*2;          // later reused as ctx
  u16* Vtb = (u16*)(ws + off); off += (size_t)4096*2048*2;
  if (ws_size < off) return;   // insufficient scratch — bail (will fail validation loudly)

  cvt_f32_bf16<<<4096, 256, 0, stream>>>(x,  xbf, 4096*2048);
  cvt_f32_bf16<<<2048, 256, 0, stream>>>(Wq, wqb, 2048*2048);
  cvt_f32_bf16<<<2048, 256, 0, stream>>>(Wk, wkb, 2048*2048);
  cvt_f32_bf16<<<2048, 256, 0, stream>>>(Wv, wvb, 2048*2048);
  cvt_f32_bf16<<<2048, 256, 0, stream>>>(Wo, wob, 2048*2048);

  lora_xa_kernel<3, 0><<<1024, 256, 0, stream>>>((const void*)x, Aq, Ak, Av, xa);

  // Q (swizzled, pre-scaled into exp2 domain), K (swizzled), V (plain)
  gemm_fused<<<dim3(16,32), 256, 0, stream>>>(xbf, wqb, bq, Bq, xa,        Qb, 0, 1, QSCALE*LOG2E);
  gemm_fused<<<dim3(16,32), 256, 0, stream>>>(xbf, wkb, bk, Bk, xa+32768,  Kb, 0, 1, 1.0f);
  gemm_fused<<<dim3(16,32), 256, 0, stream>>>(xbf, wvb, bv, Bv, xa+65536,  Vb, 0, 0, 1.0f);

  transpose_v<<<dim3(32,64), 256, 0, stream>>>(Vb, Vtb);

  attn_kernel<<<dim3(16,32), 256, 0, stream>>>(Qb, Kb, Vtb, Vb);   // ctx -> Vb (V dead after transpose)

  lora_xa_kernel<1, 1><<<1024, 256, 0, stream>>>((const void*)Vb, Ao, Ao, Ao, xa+98304);

  gemm_fused<<<dim3(16,32), 256, 0, stream>>>(Vb, wob, bo, Bo, xa+98304, d_out, 1, 0, 1.0f);
}

// Round 4
// 364.888 us; speedup vs baseline: 1.2186x; 1.0734x over previous
//
#include <hip/hip_runtime.h>
#include <stdint.h>

typedef unsigned short u16;
typedef unsigned int   u32;
typedef __bf16  bf16x8 __attribute__((ext_vector_type(8)));
typedef float   f32x4  __attribute__((ext_vector_type(4)));

#define LORA_SCALE 2.0f
#define QSCALE 0.08838834764831845f   // 1/sqrt(128)
#define LOG2E  1.4426950408889634f
#define RESCALE_THR 8.0f

__device__ __forceinline__ u16 f2bf(float f){
  u32 u = __builtin_bit_cast(u32, f);
  u32 r = (u + 0x7fffu + ((u >> 16) & 1u)) >> 16;   // RNE
  return (u16)r;
}
__device__ __forceinline__ float bf2f(u16 v){
  return __builtin_bit_cast(float, ((u32)v) << 16);
}
// pack 2 f32 -> 2 bf16 in one VALU op (no builtin on gfx950; T12 recipe)
__device__ __forceinline__ u32 cvt_pk_bf16(float lo, float hi){
  u32 d;
  asm("v_cvt_pk_bf16_f32 %0, %1, %2" : "=v"(d) : "v"(lo), "v"(hi));
  return d;
}

typedef __attribute__((address_space(3))) u32 lds_u32_t;
typedef __attribute__((address_space(1))) const u32 g_u32_t;

// async global->LDS, 16B per lane; LDS dest = wave-uniform base + lane*16
__device__ __forceinline__ void gload16(const void* g, void* l){
  __builtin_amdgcn_global_load_lds((g_u32_t*)(unsigned long long)g,
                                   (lds_u32_t*)(u32)(unsigned long long)l,
                                   16, 0, 0);
}

// ---------------- 4x W fp32 -> bf16 convert, one launch ----------------
// blockIdx>>11 selects matrix: 0..2 -> wqkv slab, 3 -> wo
__global__ __launch_bounds__(256) void cvt_w4(const float* __restrict__ W0,
    const float* __restrict__ W1, const float* __restrict__ W2,
    const float* __restrict__ W3, u16* __restrict__ wqkv, u16* __restrict__ wo){
  int sel = blockIdx.x >> 11;
  int inner = blockIdx.x & 2047;
  const float* src = sel==0 ? W0 : sel==1 ? W1 : sel==2 ? W2 : W3;
  u16* dst = sel<3 ? (wqkv + (size_t)sel*4194304) : wo;
  int i = (inner*256 + threadIdx.x) * 8;
  float4 a = *(const float4*)(src + i);
  float4 b = *(const float4*)(src + i + 4);
  u16 o[8] = {f2bf(a.x),f2bf(a.y),f2bf(a.z),f2bf(a.w),
              f2bf(b.x),f2bf(b.y),f2bf(b.z),f2bf(b.w)};
  *(uint4*)(dst + i) = *(const uint4*)o;
}

// ---------------- fused: x fp32 -> xbf bf16  AND  xa[m][r] for 3 A's ----------------
__global__ __launch_bounds__(256) void lora_x_fused(const float* __restrict__ x,
    const float* __restrict__ A0, const float* __restrict__ A1, const float* __restrict__ A2,
    float* __restrict__ xout, u16* __restrict__ xbf){
  int w = threadIdx.x >> 6, lane = threadIdx.x & 63;
  int m = blockIdx.x * 4 + w;
  float acc[3][8];
  #pragma unroll
  for (int g=0; g<3; ++g)
    #pragma unroll
    for (int r=0; r<8; ++r) acc[g][r] = 0.f;
  const float* As[3] = {A0, A1, A2};
  #pragma unroll 1
  for (int it=0; it<8; ++it){
    int k = it*256 + lane*4;
    float4 xv = *(const float4*)(x + (size_t)m*2048 + k);
    u16 o[4] = {f2bf(xv.x), f2bf(xv.y), f2bf(xv.z), f2bf(xv.w)};
    *(uint2*)(xbf + (size_t)m*2048 + k) = *(const uint2*)o;
    #pragma unroll
    for (int g=0; g<3; ++g){
      const float* Ag = As[g];
      #pragma unroll
      for (int r=0; r<8; ++r){
        float4 av = *(const float4*)(Ag + r*2048 + k);
        acc[g][r] += xv.x*av.x + xv.y*av.y + xv.z*av.z + xv.w*av.w;
      }
    }
  }
  #pragma unroll
  for (int g=0; g<3; ++g)
    #pragma unroll
    for (int r=0; r<8; ++r){
      float v = acc[g][r];
      #pragma unroll
      for (int off=32; off; off>>=1) v += __shfl_xor(v, off);
      if (lane == 0) xout[g*32768 + m*8 + r] = v;
    }
}

// ---------------- LoRA stage 1 (ctx bf16 path) ----------------
__global__ __launch_bounds__(256) void lora_xa_bf16(const u16* __restrict__ xin,
    const float* __restrict__ A0, float* __restrict__ xout){
  int w = threadIdx.x >> 6, lane = threadIdx.x & 63;
  int m = blockIdx.x * 4 + w;
  float acc[8];
  #pragma unroll
  for (int r=0; r<8; ++r) acc[r] = 0.f;
  #pragma unroll 1
  for (int it=0; it<8; ++it){
    int k = it*256 + lane*4;
    ushort4 u = *(const ushort4*)(xin + (size_t)m*2048 + k);
    float4 xv = {bf2f(u.x), bf2f(u.y), bf2f(u.z), bf2f(u.w)};
    #pragma unroll
    for (int r=0; r<8; ++r){
      float4 av = *(const float4*)(A0 + r*2048 + k);
      acc[r] += xv.x*av.x + xv.y*av.y + xv.z*av.z + xv.w*av.w;
    }
  }
  #pragma unroll
  for (int r=0; r<8; ++r){
    float v = acc[r];
    #pragma unroll
    for (int off=32; off; off>>=1) v += __shfl_xor(v, off);
    if (lane == 0) xout[m*8 + r] = v;
  }
}

// ---------------- fused QKV GEMM: out_s = xbf @ Wqkv_s^T + bias_s + 2*(xa_s @ lB_s^T) ----------------
// W concatenated [6144][2048]; n-tile selects {q,k,v} stream (uniform per block).
__global__ __launch_bounds__(256, 2) void gemm_qkv(
    const u16* __restrict__ A, const u16* __restrict__ W,
    const float* __restrict__ bq, const float* __restrict__ bk, const float* __restrict__ bv,
    const float* __restrict__ lBq, const float* __restrict__ lBk, const float* __restrict__ lBv,
    const float* __restrict__ xa, u16* __restrict__ Qb, u16* __restrict__ Kb, u16* __restrict__ Vb){
  const int Kd = 2048;
  __shared__ u16 Ash[128*32];
  __shared__ u16 Bsh[128*32];
  int tid = threadIdx.x, w = tid >> 6, lane = tid & 63;
  int l15 = lane & 15, l4 = lane >> 4;
  int n0g = blockIdx.x * 128, m0 = blockIdx.y * 128;
  int which = blockIdx.x >> 4;                 // 0=q 1=k 2=v
  int n0 = n0g & 2047;                         // local col base
  const float* bias = which==0 ? bq : which==1 ? bk : bv;
  const float* lB   = which==0 ? lBq : which==1 ? lBk : lBv;
  const float* xs   = xa + which*32768;
  u16* outp         = which==0 ? Qb : which==1 ? Kb : Vb;
  int swz = (which <= 1);
  float oscale = (which == 0) ? QSCALE*LOG2E : 1.0f;
  int wm = w >> 1, wn = w & 1;
  f32x4 acc[4][4];
  #pragma unroll
  for (int mi=0; mi<4; mi++)
    #pragma unroll
    for (int ni=0; ni<4; ni++) acc[mi][ni] = (f32x4){0.f,0.f,0.f,0.f};

  const u16* Arow = A + (size_t)m0 * Kd;
  const u16* Wrow = W + (size_t)n0g * Kd;
  for (int kt = 0; kt < Kd; kt += 32){
    __syncthreads();
    #pragma unroll
    for (int i=0; i<2; ++i){
      int e = (i*256 + tid) * 8;
      int r = e >> 5, c = e & 31;
      gload16(Arow + (size_t)r*Kd + kt + c, (char*)Ash + i*4096 + w*1024);
      gload16(Wrow + (size_t)r*Kd + kt + c, (char*)Bsh + i*4096 + w*1024);
    }
    __syncthreads();
    bf16x8 af[4], bfv[4];
    #pragma unroll
    for (int mi=0; mi<4; mi++)
      af[mi] = *(const bf16x8*)(Ash + (wm*64 + mi*16 + l15)*32 + l4*8);
    #pragma unroll
    for (int ni=0; ni<4; ni++)
      bfv[ni] = *(const bf16x8*)(Bsh + (wn*64 + ni*16 + l15)*32 + l4*8);
    #pragma unroll
    for (int mi=0; mi<4; mi++)
      #pragma unroll
      for (int ni=0; ni<4; ni++)
        acc[mi][ni] = __builtin_amdgcn_mfma_f32_16x16x32_bf16(af[mi], bfv[ni], acc[mi][ni], 0, 0, 0);
  }
  float bvv[4]; float4 lb0[4], lb1[4];
  #pragma unroll
  for (int ni=0; ni<4; ni++){
    int col = n0 + wn*64 + ni*16 + l15;
    bvv[ni] = bias[col];
    lb0[ni] = *(const float4*)(lB + col*8);
    lb1[ni] = *(const float4*)(lB + col*8 + 4);
  }
  #pragma unroll
  for (int mi=0; mi<4; mi++)
    #pragma unroll
    for (int j=0; j<4; j++){
      int r = m0 + wm*64 + mi*16 + l4*4 + j;
      float4 xv0 = *(const float4*)(xs + (size_t)r*8);
      float4 xv1 = *(const float4*)(xs + (size_t)r*8 + 4);
      #pragma unroll
      for (int ni=0; ni<4; ni++){
        int col = n0 + wn*64 + ni*16 + l15;
        float v = acc[mi][ni][j] + bvv[ni] + LORA_SCALE * (
            xv0.x*lb0[ni].x + xv0.y*lb0[ni].y + xv0.z*lb0[ni].z + xv0.w*lb0[ni].w +
            xv1.x*lb1[ni].x + xv1.y*lb1[ni].y + xv1.z*lb1[ni].z + xv1.w*lb1[ni].w);
        v *= oscale;
        int cs = swz ? (col ^ ((r & 7) << 3)) : col;
        outp[(size_t)r*2048 + cs] = f2bf(v);
      }
    }
}

// ---------------- O projection GEMM: d_out = ctx @ Wo^T + bo + 2*(xa_o @ Bo^T), fp32 out ----------------
__global__ __launch_bounds__(256, 2) void gemm_o(
    const u16* __restrict__ A, const u16* __restrict__ W,
    const float* __restrict__ bias, const float* __restrict__ lB,
    const float* __restrict__ xa, float* __restrict__ outp){
  const int Kd = 2048, Nd = 2048;
  __shared__ u16 Ash[128*32];
  __shared__ u16 Bsh[128*32];
  int tid = threadIdx.x, w = tid >> 6, lane = tid & 63;
  int l15 = lane & 15, l4 = lane >> 4;
  int n0 = blockIdx.x * 128, m0 = blockIdx.y * 128;
  int wm = w >> 1, wn = w & 1;
  f32x4 acc[4][4];
  #pragma unroll
  for (int mi=0; mi<4; mi++)
    #pragma unroll
    for (int ni=0; ni<4; ni++) acc[mi][ni] = (f32x4){0.f,0.f,0.f,0.f};

  const u16* Arow = A + (size_t)m0 * Kd;
  const u16* Wrow = W + (size_t)n0 * Kd;
  for (int kt = 0; kt < Kd; kt += 32){
    __syncthreads();
    #pragma unroll
    for (int i=0; i<2; ++i){
      int e = (i*256 + tid) * 8;
      int r = e >> 5, c = e & 31;
      gload16(Arow + (size_t)r*Kd + kt + c, (char*)Ash + i*4096 + w*1024);
      gload16(Wrow + (size_t)r*Kd + kt + c, (char*)Bsh + i*4096 + w*1024);
    }
    __syncthreads();
    bf16x8 af[4], bfv[4];
    #pragma unroll
    for (int mi=0; mi<4; mi++)
      af[mi] = *(const bf16x8*)(Ash + (wm*64 + mi*16 + l15)*32 + l4*8);
    #pragma unroll
    for (int ni=0; ni<4; ni++)
      bfv[ni] = *(const bf16x8*)(Bsh + (wn*64 + ni*16 + l15)*32 + l4*8);
    #pragma unroll
    for (int mi=0; mi<4; mi++)
      #pragma unroll
      for (int ni=0; ni<4; ni++)
        acc[mi][ni] = __builtin_amdgcn_mfma_f32_16x16x32_bf16(af[mi], bfv[ni], acc[mi][ni], 0, 0, 0);
  }
  float bv[4]; float4 lb0[4], lb1[4];
  #pragma unroll
  for (int ni=0; ni<4; ni++){
    int col = n0 + wn*64 + ni*16 + l15;
    bv[ni] = bias[col];
    lb0[ni] = *(const float4*)(lB + col*8);
    lb1[ni] = *(const float4*)(lB + col*8 + 4);
  }
  #pragma unroll
  for (int mi=0; mi<4; mi++)
    #pragma unroll
    for (int j=0; j<4; j++){
      int r = m0 + wm*64 + mi*16 + l4*4 + j;
      float4 xv0 = *(const float4*)(xa + (size_t)r*8);
      float4 xv1 = *(const float4*)(xa + (size_t)r*8 + 4);
      #pragma unroll
      for (int ni=0; ni<4; ni++){
        int col = n0 + wn*64 + ni*16 + l15;
        float v = acc[mi][ni][j] + bv[ni] + LORA_SCALE * (
            xv0.x*lb0[ni].x + xv0.y*lb0[ni].y + xv0.z*lb0[ni].z + xv0.w*lb0[ni].w +
            xv1.x*lb1[ni].x + xv1.y*lb1[ni].y + xv1.z*lb1[ni].z + xv1.w*lb1[ni].w);
        outp[(size_t)r*Nd + col] = v;
      }
    }
}

// ---------------- V transpose: V[4096][2048] -> Vt[bh][d][s] (kv-swizzled) ----------------
__global__ __launch_bounds__(256) void transpose_v(const u16* __restrict__ V,
                                                   u16* __restrict__ Vt){
  __shared__ u16 tile[64*80];
  int tid = threadIdx.x;
  int f0 = blockIdx.x * 64, m0 = blockIdx.y * 64;
  int i = tid >> 2, j0 = (tid & 3) * 16;
  #pragma unroll
  for (int kk=0; kk<16; kk+=8){
    uint4 u = *(const uint4*)(V + (size_t)(m0 + i)*2048 + f0 + j0 + kk);
    *(uint4*)(tile + i*80 + j0 + kk) = u;
  }
  __syncthreads();
  int j = tid >> 2, i0 = (tid & 3) * 16;
  int b = m0 >> 11, s0 = m0 & 2047;
  int h = f0 >> 7, d = (f0 & 127) + j;
  int c = (d & 7) << 3;
  size_t obase = ((size_t)((b*16 + h)*128 + d)) * 2048 + s0;
  #pragma unroll
  for (int kk=0; kk<16; kk+=8){
    u16 v8[8];
    #pragma unroll
    for (int u2=0; u2<8; ++u2) v8[u2] = tile[(i0+kk+u2)*80 + j];
    *(uint4*)(Vt + obase + ((i0+kk) ^ c)) = *(const uint4*)v8;   // (x^c)+u == (x+u)^c, c%8==0
  }
}

// ---------------- flash attention: QBLK=128, KVBLK=64, 4 waves x 32 q-rows ----------------
// Swapped-operand (S^T = mfma(K,Q)); in-lane softmax; T13 defer-max; double-buffered
// K/V; T1 XCD-aware block remap (each XCD owns 4 heads -> K/V L2-resident).
__global__ __launch_bounds__(256, 2) void attn_kernel(
    const u16* __restrict__ Q, const u16* __restrict__ K,
    const u16* __restrict__ Vt, u16* __restrict__ ctx){
  __shared__ u16 buf[2][16384];  // per buffer: K [64][128] (8192 u16) then V [128][64]
  __shared__ u16 Psh[4*32*64];   // 16 KB: per-wave P [32 q][64 kv], XOR-swizzled
  int tid = threadIdx.x, w = tid >> 6, lane = tid & 63;
  int l15 = lane & 15, l4 = lane >> 4;
  // T1: XCD-aware remap. 512 blocks, 8 XCDs (wgid%8 = XCD): XCD k gets bh in [4k,4k+4)
  int lin = blockIdx.x;
  int virt = (lin & 7) * 64 + (lin >> 3);
  int qt = virt & 15, bh = virt >> 4;
  int b = bh >> 4, h = bh & 15;
  const u16* Qg = Q + (size_t)(b*2048 + qt*128) * 2048 + h*128;
  const u16* Kg = K + (size_t)(b*2048) * 2048 + h*128;
  const u16* Vg = Vt + (size_t)bh * 128 * 2048;

  // prologue: Q -> buf[1], kv-tile 0 -> buf[0]
  #pragma unroll
  for (int i=0; i<8; ++i){
    int e = (i*256 + tid) * 8;
    int r = e >> 7, cc = e & 127;
    gload16(Qg + (size_t)r*2048 + cc, (char*)buf[1] + i*4096 + w*1024);
  }
  #pragma unroll
  for (int i=0; i<4; ++i){
    int e = (i*256 + tid) * 8;
    int r = e >> 7, cc = e & 127;
    gload16(Kg + (size_t)r*2048 + cc, (char*)buf[0] + i*4096 + w*1024);
    int dd = e >> 6, c2 = e & 63;
    gload16(Vg + (size_t)dd*2048 + c2, (char*)buf[0] + 16384 + i*4096 + w*1024);
  }
  __syncthreads();   // drains vmcnt

  bf16x8 qf[2][4];   // Q rows (pre-scaled by log2e/sqrt(dk)); used as B operand
  #pragma unroll
  for (int mi=0; mi<2; mi++){
    int r = w*32 + mi*16 + l15;
    #pragma unroll
    for (int kb=0; kb<4; kb++){
      int cc = (kb*32 + l4*8) ^ ((r & 7) << 3);
      qf[mi][kb] = *(const bf16x8*)(buf[1] + r*128 + cc);
    }
  }
  __syncthreads();   // all waves done with Q region before it becomes buffer 1

  // O^T accumulator: ctxa[mi][nd] reg j -> d = nd*16 + l4*4 + j, q = mi*16 + l15
  f32x4 ctxa[2][8];
  #pragma unroll
  for (int mi=0; mi<2; mi++)
    #pragma unroll
    for (int nd=0; nd<8; nd++) ctxa[mi][nd] = (f32x4){0.f,0.f,0.f,0.f};
  float mrun[2] = {-3.0e38f, -3.0e38f};
  float lrun[2] = {0.f, 0.f};

  char* PwB = (char*)(Psh + w * (32*64));   // byte base of this wave's P tile
  int psw = (l15 & 7) << 4;                 // byte XOR swizzle for P (row = mi*16+l15)

  for (int t = 0; t < 32; ++t){
    int cur = t & 1;
    const u16* Kc = buf[cur];
    const u16* Vc = buf[cur] + 8192;
    // prefetch next kv tile into the other buffer (latency hides under compute)
    if (t + 1 < 32){
      int kvn = (t + 1) * 64;
      char* bn = (char*)buf[cur ^ 1];
      #pragma unroll
      for (int i=0; i<4; ++i){
        int e = (i*256 + tid) * 8;
        int r = e >> 7, cc = e & 127;
        gload16(Kg + (size_t)(kvn + r)*2048 + cc, bn + i*4096 + w*1024);
        int dd = e >> 6, c2 = e & 63;
        gload16(Vg + (size_t)dd*2048 + kvn + c2, bn + 16384 + i*4096 + w*1024);
      }
    }
    // S^T = mfma(K, Q): lane reg j of s[mi][ni]: kv = ni*16 + l4*4 + j, q = mi*16 + l15
    f32x4 s[2][4];
    #pragma unroll
    for (int mi=0; mi<2; mi++)
      #pragma unroll
      for (int ni=0; ni<4; ni++) s[mi][ni] = (f32x4){0.f,0.f,0.f,0.f};
    __builtin_amdgcn_s_setprio(1);
    #pragma unroll
    for (int kb=0; kb<4; kb++){
      #pragma unroll
      for (int ni=0; ni<4; ni++){
        int r = ni*16 + l15;
        int cc = (kb*32 + l4*8) ^ ((r & 7) << 3);
        bf16x8 kf = *(const bf16x8*)(Kc + r*128 + cc);
        s[0][ni] = __builtin_amdgcn_mfma_f32_16x16x32_bf16(kf, qf[0][kb], s[0][ni], 0, 0, 0);
        s[1][ni] = __builtin_amdgcn_mfma_f32_16x16x32_bf16(kf, qf[1][kb], s[1][ni], 0, 0, 0);
      }
    }
    __builtin_amdgcn_s_setprio(0);
    // in-lane tile max per q-row (16 values) + cross-l4 combine
    float pm[2];
    #pragma unroll
    for (int mi=0; mi<2; mi++){
      float v = s[mi][0][0];
      #pragma unroll
      for (int ni=0; ni<4; ni++)
        #pragma unroll
        for (int j=0; j<4; j++) v = fmaxf(v, s[mi][ni][j]);
      v = fmaxf(v, __shfl_xor(v, 16));
      v = fmaxf(v, __shfl_xor(v, 32));
      pm[mi] = v;
    }
    // T13 defer-max: rescale only when max grows beyond THR (exp2 domain)
    bool need = (pm[0] > mrun[0] + RESCALE_THR) || (pm[1] > mrun[1] + RESCALE_THR);
    if (__any(need)){
      #pragma unroll
      for (int mi=0; mi<2; mi++){
        float mnew = fmaxf(mrun[mi], pm[mi]);
        float cr = exp2f(mrun[mi] - mnew);
        lrun[mi] *= cr;
        mrun[mi] = mnew;
        #pragma unroll
        for (int nd=0; nd<8; nd++) ctxa[mi][nd] *= cr;
      }
    }
    // P = exp2(S - m), pack to bf16, ds_write_b64 (4 consecutive kv per write)
    #pragma unroll
    for (int mi=0; mi<2; mi++){
      float ps = 0.f;
      #pragma unroll
      for (int ni=0; ni<4; ni++){
        float p0 = exp2f(s[mi][ni][0] - mrun[mi]);
        float p1 = exp2f(s[mi][ni][1] - mrun[mi]);
        float p2 = exp2f(s[mi][ni][2] - mrun[mi]);
        float p3 = exp2f(s[mi][ni][3] - mrun[mi]);
        ps += (p0 + p1) + (p2 + p3);
        uint2 pk = {cvt_pk_bf16(p0, p1), cvt_pk_bf16(p2, p3)};
        *(uint2*)(PwB + (mi*16 + l15)*128 + ((ni*32 + l4*8) ^ psw)) = pk;
      }
      ps += __shfl_xor(ps, 16);
      ps += __shfl_xor(ps, 32);
      lrun[mi] += ps;
    }
    // PV (swapped): O^T += mfma(V^T, P); B-frag = P[q=l15(+16mi)][kv=l4*8..+8]
    bf16x8 pb[2][2];
    #pragma unroll
    for (int mi=0; mi<2; mi++)
      #pragma unroll
      for (int kvb=0; kvb<2; kvb++)
        pb[mi][kvb] = *(const bf16x8*)(PwB + (mi*16 + l15)*128 + ((kvb*64 + l4*16) ^ psw));
    __builtin_amdgcn_s_setprio(1);
    #pragma unroll
    for (int nd=0; nd<8; nd++){
      int dd = nd*16 + l15;
      int sw = (dd & 7) << 3;
      #pragma unroll
      for (int kvb=0; kvb<2; kvb++){
        bf16x8 vf = *(const bf16x8*)(Vc + dd*64 + ((kvb*32 + l4*8) ^ sw));
        ctxa[0][nd] = __builtin_amdgcn_mfma_f32_16x16x32_bf16(vf, pb[0][kvb], ctxa[0][nd], 0, 0, 0);
        ctxa[1][nd] = __builtin_amdgcn_mfma_f32_16x16x32_bf16(vf, pb[1][kvb], ctxa[1][nd], 0, 0, 0);
      }
    }
    __builtin_amdgcn_s_setprio(0);
    __syncthreads();   // implicit vmcnt(0): next buffer ready; all waves done with cur
  }
  // epilogue: normalize, transpose through per-wave LDS region, coalesced store
  char* OwB = (char*)buf[0] + w*8192;   // [32 q][128 d] bf16, XOR-swizzled
  #pragma unroll
  for (int mi=0; mi<2; mi++){
    float inv = 1.0f / lrun[mi];
    #pragma unroll
    for (int nd=0; nd<8; nd++){
      f32x4 c = ctxa[mi][nd] * inv;
      uint2 pk = {cvt_pk_bf16(c[0], c[1]), cvt_pk_bf16(c[2], c[3])};
      *(uint2*)(OwB + (mi*16 + l15)*256 + ((nd*32 + l4*8) ^ psw)) = pk;
    }
  }
  #pragma unroll
  for (int i=0; i<8; ++i){
    int row = i*4 + l4;          // 0..31
    int colb = l15*16;           // byte col 0..240
    uint4 v = *(const uint4*)(OwB + row*256 + (colb ^ ((row & 7) << 4)));
    int srow = qt*128 + w*32 + row;
    *(uint4*)(ctx + ((size_t)(b*2048 + srow))*2048 + h*128 + colb/2) = v;
  }
}

// ---------------- launcher ----------------
extern "C" void kernel_launch(void* const* d_in, const int* in_sizes, int n_in,
                              void* d_out, int out_size, void* d_ws, size_t ws_size,
                              hipStream_t stream){
  const float* x  = (const float*)d_in[0];
  const float* Wq = (const float*)d_in[1];  const float* bq = (const float*)d_in[2];
  const float* Aq = (const float*)d_in[3];  const float* Bq = (const float*)d_in[4];
  const float* Wk = (const float*)d_in[5];  const float* bk = (const float*)d_in[6];
  const float* Ak = (const float*)d_in[7];  const float* Bk = (const float*)d_in[8];
  const float* Wv = (const float*)d_in[9];  const float* bv = (const float*)d_in[10];
  const float* Av = (const float*)d_in[11]; const float* Bv = (const float*)d_in[12];
  const float* Wo = (const float*)d_in[13]; const float* bo = (const float*)d_in[14];
  const float* Ao = (const float*)d_in[15]; const float* Bo = (const float*)d_in[16];

  char* ws = (char*)d_ws;
  size_t off = 0;
  u16* xbf  = (u16*)(ws + off); off += (size_t)4096*2048*2;          // 16 MB
  u16* wqkv = (u16*)(ws + off); off += (size_t)3*2048*2048*2;        // 24 MB
  u16* wob  = (u16*)(ws + off); off += (size_t)2048*2048*2;          // 8 MB
  float* xa = (float*)(ws + off); off += (size_t)4*32768*4;          // 4 slabs [4096][8]
  u16* Qb  = (u16*)(ws + off); off += (size_t)4096*2048*2;
  u16* Kb  = (u16*)(ws + off); off += (size_t)4096*2048*2;
  u16* Vb  = (u16*)(ws + off); off += (size_t)4096*2048*2;           // later reused as ctx
  u16* Vtb = (u16*)(ws + off); off += (size_t)4096*2048*2;
  if (ws_size < off) return;   // insufficient scratch — bail (will fail validation loudly)

  cvt_w4<<<8192, 256, 0, stream>>>(Wq, Wk, Wv, Wo, wqkv, wob);
  lora_x_fused<<<1024, 256, 0, stream>>>(x, Aq, Ak, Av, xa, xbf);

  gemm_qkv<<<dim3(48,32), 256, 0, stream>>>(xbf, wqkv, bq, bk, bv, Bq, Bk, Bv, xa, Qb, Kb, Vb);

  transpose_v<<<dim3(32,64), 256, 0, stream>>>(Vb, Vtb);

  attn_kernel<<<512, 256, 0, stream>>>(Qb, Kb, Vtb, Vb);   // ctx -> Vb (V dead after transpose)

  lora_xa_bf16<<<1024, 256, 0, stream>>>(Vb, Ao, xa+98304);

  gemm_o<<<dim3(16,32), 256, 0, stream>>>(Vb, wob, bo, Bo, xa+98304, (float*)d_out);
}

// Round 5
// 357.198 us; speedup vs baseline: 1.2448x; 1.0215x over previous
//
#include <hip/hip_runtime.h>
#include <stdint.h>

typedef unsigned short u16;
typedef unsigned int   u32;
typedef __bf16  bf16x8 __attribute__((ext_vector_type(8)));
typedef float   f32x4  __attribute__((ext_vector_type(4)));

#define LORA_SCALE 2.0f
#define QSCALE 0.08838834764831845f   // 1/sqrt(128)
#define LOG2E  1.4426950408889634f
#define RESCALE_THR 8.0f

__device__ __forceinline__ u16 f2bf(float f){
  u32 u = __builtin_bit_cast(u32, f);
  u32 r = (u + 0x7fffu + ((u >> 16) & 1u)) >> 16;   // RNE
  return (u16)r;
}
__device__ __forceinline__ float bf2f(u16 v){
  return __builtin_bit_cast(float, ((u32)v) << 16);
}
// pack 2 f32 -> 2 bf16 in one VALU op (no builtin on gfx950; T12 recipe)
__device__ __forceinline__ u32 cvt_pk_bf16(float lo, float hi){
  u32 d;
  asm("v_cvt_pk_bf16_f32 %0, %1, %2" : "=v"(d) : "v"(lo), "v"(hi));
  return d;
}

typedef __attribute__((address_space(3))) u32 lds_u32_t;
typedef __attribute__((address_space(1))) const u32 g_u32_t;

// async global->LDS, 16B per lane; LDS dest = wave-uniform base + lane*16
__device__ __forceinline__ void gload16(const void* g, void* l){
  __builtin_amdgcn_global_load_lds((g_u32_t*)(unsigned long long)g,
                                   (lds_u32_t*)(u32)(unsigned long long)l,
                                   16, 0, 0);
}

// ---------------- 4x W fp32 -> bf16 convert, one launch ----------------
__global__ __launch_bounds__(256) void cvt_w4(const float* __restrict__ W0,
    const float* __restrict__ W1, const float* __restrict__ W2,
    const float* __restrict__ W3, u16* __restrict__ wqkv, u16* __restrict__ wo){
  int sel = blockIdx.x >> 11;
  int inner = blockIdx.x & 2047;
  const float* src = sel==0 ? W0 : sel==1 ? W1 : sel==2 ? W2 : W3;
  u16* dst = sel<3 ? (wqkv + (size_t)sel*4194304) : wo;
  int i = (inner*256 + threadIdx.x) * 8;
  float4 a = *(const float4*)(src + i);
  float4 b = *(const float4*)(src + i + 4);
  u16 o[8] = {f2bf(a.x),f2bf(a.y),f2bf(a.z),f2bf(a.w),
              f2bf(b.x),f2bf(b.y),f2bf(b.z),f2bf(b.w)};
  *(uint4*)(dst + i) = *(const uint4*)o;
}

// ---------------- fused: x fp32 -> xbf bf16  AND  xa[m][r] for 3 A's ----------------
__global__ __launch_bounds__(256) void lora_x_fused(const float* __restrict__ x,
    const float* __restrict__ A0, const float* __restrict__ A1, const float* __restrict__ A2,
    float* __restrict__ xout, u16* __restrict__ xbf){
  int w = threadIdx.x >> 6, lane = threadIdx.x & 63;
  int m = blockIdx.x * 4 + w;
  float acc[3][8];
  #pragma unroll
  for (int g=0; g<3; ++g)
    #pragma unroll
    for (int r=0; r<8; ++r) acc[g][r] = 0.f;
  const float* As[3] = {A0, A1, A2};
  #pragma unroll 1
  for (int it=0; it<8; ++it){
    int k = it*256 + lane*4;
    float4 xv = *(const float4*)(x + (size_t)m*2048 + k);
    u16 o[4] = {f2bf(xv.x), f2bf(xv.y), f2bf(xv.z), f2bf(xv.w)};
    *(uint2*)(xbf + (size_t)m*2048 + k) = *(const uint2*)o;
    #pragma unroll
    for (int g=0; g<3; ++g){
      const float* Ag = As[g];
      #pragma unroll
      for (int r=0; r<8; ++r){
        float4 av = *(const float4*)(Ag + r*2048 + k);
        acc[g][r] += xv.x*av.x + xv.y*av.y + xv.z*av.z + xv.w*av.w;
      }
    }
  }
  #pragma unroll
  for (int g=0; g<3; ++g)
    #pragma unroll
    for (int r=0; r<8; ++r){
      float v = acc[g][r];
      #pragma unroll
      for (int off=32; off; off>>=1) v += __shfl_xor(v, off);
      if (lane == 0) xout[g*32768 + m*8 + r] = v;
    }
}

// ---------------- LoRA stage 1 (ctx bf16 path) ----------------
__global__ __launch_bounds__(256) void lora_xa_bf16(const u16* __restrict__ xin,
    const float* __restrict__ A0, float* __restrict__ xout){
  int w = threadIdx.x >> 6, lane = threadIdx.x & 63;
  int m = blockIdx.x * 4 + w;
  float acc[8];
  #pragma unroll
  for (int r=0; r<8; ++r) acc[r] = 0.f;
  #pragma unroll 1
  for (int it=0; it<8; ++it){
    int k = it*256 + lane*4;
    ushort4 u = *(const ushort4*)(xin + (size_t)m*2048 + k);
    float4 xv = {bf2f(u.x), bf2f(u.y), bf2f(u.z), bf2f(u.w)};
    #pragma unroll
    for (int r=0; r<8; ++r){
      float4 av = *(const float4*)(A0 + r*2048 + k);
      acc[r] += xv.x*av.x + xv.y*av.y + xv.z*av.z + xv.w*av.w;
    }
  }
  #pragma unroll
  for (int r=0; r<8; ++r){
    float v = acc[r];
    #pragma unroll
    for (int off=32; off; off>>=1) v += __shfl_xor(v, off);
    if (lane == 0) xout[m*8 + r] = v;
  }
}

// ---------------- pipelined GEMM core: depth-2 counted-vmcnt, T2 chunk swizzle ----------------
// 128x128 tile, BK=32, 4 waves (2x2), 3 LDS buffers (A 8KB + B 8KB each).
// Per iter t: stage tile t+2 -> buf[(t+2)%3]; ds_read+MFMA tile t from buf[t%3];
// s_waitcnt vmcnt(4) (tile t+1 resident, t+2 in flight); one raw s_barrier.
// LDS chunk swizzle: 16B-chunk ch at row r holds global chunk ch^((r>>1)&3)
// (involution; applied on gload source AND ds_read addr) -> 8-way -> 2-way conflicts.
__device__ __forceinline__ void gemm_core_pipe(
    const u16* __restrict__ Arow, const u16* __restrict__ Wrow,
    u16* lds, int tid, f32x4 acc[4][4]){
  const int Kd = 2048, NT = 64;
  int w = tid >> 6, lane = tid & 63;
  int l15 = lane & 15, l4 = lane >> 4;
  int wm = w >> 1, wn = w & 1;
  // per-thread staging geometry (2 chunks per matrix, rows 0..63 then 64..127)
  int d0 = tid*16,        r0 = d0>>6, c0 = ((((d0>>4)&3) ^ ((r0>>1)&3))<<3);
  int d1 = 4096 + tid*16, r1 = d1>>6, c1 = ((((d1>>4)&3) ^ ((r1>>1)&3))<<3);

  auto STAGE = [&](int t, int pb){
    int kt = t*32;
    char* LA = (char*)lds + pb*16384;
    char* LB = LA + 8192;
    gload16(Arow + (size_t)r0*Kd + kt + c0, LA + w*1024);
    gload16(Wrow + (size_t)r0*Kd + kt + c0, LB + w*1024);
    gload16(Arow + (size_t)r1*Kd + kt + c1, LA + 4096 + w*1024);
    gload16(Wrow + (size_t)r1*Kd + kt + c1, LB + 4096 + w*1024);
  };

  STAGE(0,0); STAGE(1,1);
  asm volatile("s_waitcnt vmcnt(4)" ::: "memory");   // tile 0 resident
  __builtin_amdgcn_s_barrier();

  int pc = 0, pn = 2;
  #pragma unroll 1
  for (int t=0; t<NT; ++t){
    if (t < NT-2) STAGE(t+2, pn);
    const u16* LA = lds + pc*8192;
    const u16* LB = LA + 4096;
    bf16x8 af[4], bfv[4];
    #pragma unroll
    for (int mi=0; mi<4; mi++){
      int r = wm*64 + mi*16 + l15;
      af[mi] = *(const bf16x8*)(LA + r*32 + ((l4 ^ ((r>>1)&3))<<3));
    }
    #pragma unroll
    for (int ni=0; ni<4; ni++){
      int r = wn*64 + ni*16 + l15;
      bfv[ni] = *(const bf16x8*)(LB + r*32 + ((l4 ^ ((r>>1)&3))<<3));
    }
    __builtin_amdgcn_s_setprio(1);
    #pragma unroll
    for (int mi=0; mi<4; mi++)
      #pragma unroll
      for (int ni=0; ni<4; ni++)
        acc[mi][ni] = __builtin_amdgcn_mfma_f32_16x16x32_bf16(af[mi], bfv[ni], acc[mi][ni], 0, 0, 0);
    __builtin_amdgcn_s_setprio(0);
    if (t < NT-2){
      asm volatile("s_waitcnt vmcnt(4)" ::: "memory");   // tile t+1 resident; t+2 in flight
      __builtin_amdgcn_s_barrier();
    } else if (t == NT-2){
      asm volatile("s_waitcnt vmcnt(0)" ::: "memory");   // last tile resident
      __builtin_amdgcn_s_barrier();
    }
    pc = pc==2 ? 0 : pc+1;
    pn = pn==2 ? 0 : pn+1;
  }
}

// ---------------- fused QKV GEMM ----------------
__global__ __launch_bounds__(256, 3) void gemm_qkv(
    const u16* __restrict__ A, const u16* __restrict__ W,
    const float* __restrict__ bq, const float* __restrict__ bk, const float* __restrict__ bv,
    const float* __restrict__ lBq, const float* __restrict__ lBk, const float* __restrict__ lBv,
    const float* __restrict__ xa, u16* __restrict__ Qb, u16* __restrict__ Kb, u16* __restrict__ Vb){
  const int Kd = 2048;
  __shared__ u16 lds3[3*8192];   // 48 KB
  int tid = threadIdx.x, lane = tid & 63;
  int l15 = lane & 15, l4 = lane >> 4;
  int w = tid >> 6, wm = w >> 1, wn = w & 1;
  int n0g = blockIdx.x * 128, m0 = blockIdx.y * 128;
  int which = blockIdx.x >> 4;                 // 0=q 1=k 2=v
  int n0 = n0g & 2047;
  const float* bias = which==0 ? bq : which==1 ? bk : bv;
  const float* lB   = which==0 ? lBq : which==1 ? lBk : lBv;
  const float* xs   = xa + which*32768;
  u16* outp         = which==0 ? Qb : which==1 ? Kb : Vb;
  int swz = (which <= 1);
  float oscale = (which == 0) ? QSCALE*LOG2E : 1.0f;
  f32x4 acc[4][4];
  #pragma unroll
  for (int mi=0; mi<4; mi++)
    #pragma unroll
    for (int ni=0; ni<4; ni++) acc[mi][ni] = (f32x4){0.f,0.f,0.f,0.f};

  gemm_core_pipe(A + (size_t)m0*Kd, W + (size_t)n0g*Kd, lds3, tid, acc);

  float bvv[4]; float4 lb0[4], lb1[4];
  #pragma unroll
  for (int ni=0; ni<4; ni++){
    int col = n0 + wn*64 + ni*16 + l15;
    bvv[ni] = bias[col];
    lb0[ni] = *(const float4*)(lB + col*8);
    lb1[ni] = *(const float4*)(lB + col*8 + 4);
  }
  #pragma unroll
  for (int mi=0; mi<4; mi++)
    #pragma unroll
    for (int j=0; j<4; j++){
      int r = m0 + wm*64 + mi*16 + l4*4 + j;
      float4 xv0 = *(const float4*)(xs + (size_t)r*8);
      float4 xv1 = *(const float4*)(xs + (size_t)r*8 + 4);
      #pragma unroll
      for (int ni=0; ni<4; ni++){
        int col = n0 + wn*64 + ni*16 + l15;
        float v = acc[mi][ni][j] + bvv[ni] + LORA_SCALE * (
            xv0.x*lb0[ni].x + xv0.y*lb0[ni].y + xv0.z*lb0[ni].z + xv0.w*lb0[ni].w +
            xv1.x*lb1[ni].x + xv1.y*lb1[ni].y + xv1.z*lb1[ni].z + xv1.w*lb1[ni].w);
        v *= oscale;
        int cs = swz ? (col ^ ((r & 7) << 3)) : col;
        outp[(size_t)r*2048 + cs] = f2bf(v);
      }
    }
}

// ---------------- O projection GEMM (fp32 out) ----------------
__global__ __launch_bounds__(256, 3) void gemm_o(
    const u16* __restrict__ A, const u16* __restrict__ W,
    const float* __restrict__ bias, const float* __restrict__ lB,
    const float* __restrict__ xa, float* __restrict__ outp){
  const int Kd = 2048, Nd = 2048;
  __shared__ u16 lds3[3*8192];   // 48 KB
  int tid = threadIdx.x, lane = tid & 63;
  int l15 = lane & 15, l4 = lane >> 4;
  int w = tid >> 6, wm = w >> 1, wn = w & 1;
  int n0 = blockIdx.x * 128, m0 = blockIdx.y * 128;
  f32x4 acc[4][4];
  #pragma unroll
  for (int mi=0; mi<4; mi++)
    #pragma unroll
    for (int ni=0; ni<4; ni++) acc[mi][ni] = (f32x4){0.f,0.f,0.f,0.f};

  gemm_core_pipe(A + (size_t)m0*Kd, W + (size_t)n0*Kd, lds3, tid, acc);

  float bv[4]; float4 lb0[4], lb1[4];
  #pragma unroll
  for (int ni=0; ni<4; ni++){
    int col = n0 + wn*64 + ni*16 + l15;
    bv[ni] = bias[col];
    lb0[ni] = *(const float4*)(lB + col*8);
    lb1[ni] = *(const float4*)(lB + col*8 + 4);
  }
  #pragma unroll
  for (int mi=0; mi<4; mi++)
    #pragma unroll
    for (int j=0; j<4; j++){
      int r = m0 + wm*64 + mi*16 + l4*4 + j;
      float4 xv0 = *(const float4*)(xa + (size_t)r*8);
      float4 xv1 = *(const float4*)(xa + (size_t)r*8 + 4);
      #pragma unroll
      for (int ni=0; ni<4; ni++){
        int col = n0 + wn*64 + ni*16 + l15;
        float v = acc[mi][ni][j] + bv[ni] + LORA_SCALE * (
            xv0.x*lb0[ni].x + xv0.y*lb0[ni].y + xv0.z*lb0[ni].z + xv0.w*lb0[ni].w +
            xv1.x*lb1[ni].x + xv1.y*lb1[ni].y + xv1.z*lb1[ni].z + xv1.w*lb1[ni].w);
        outp[(size_t)r*Nd + col] = v;
      }
    }
}

// ---------------- V transpose: V[4096][2048] -> Vt[bh][d][s] (kv-swizzled) ----------------
__global__ __launch_bounds__(256) void transpose_v(const u16* __restrict__ V,
                                                   u16* __restrict__ Vt){
  __shared__ u16 tile[64*80];
  int tid = threadIdx.x;
  int f0 = blockIdx.x * 64, m0 = blockIdx.y * 64;
  int i = tid >> 2, j0 = (tid & 3) * 16;
  #pragma unroll
  for (int kk=0; kk<16; kk+=8){
    uint4 u = *(const uint4*)(V + (size_t)(m0 + i)*2048 + f0 + j0 + kk);
    *(uint4*)(tile + i*80 + j0 + kk) = u;
  }
  __syncthreads();
  int j = tid >> 2, i0 = (tid & 3) * 16;
  int b = m0 >> 11, s0 = m0 & 2047;
  int h = f0 >> 7, d = (f0 & 127) + j;
  int c = (d & 7) << 3;
  size_t obase = ((size_t)((b*16 + h)*128 + d)) * 2048 + s0;
  #pragma unroll
  for (int kk=0; kk<16; kk+=8){
    u16 v8[8];
    #pragma unroll
    for (int u2=0; u2<8; ++u2) v8[u2] = tile[(i0+kk+u2)*80 + j];
    *(uint4*)(Vt + obase + ((i0+kk) ^ c)) = *(const uint4*)v8;   // (x^c)+u == (x+u)^c, c%8==0
  }
}

// ---------------- flash attention: QBLK=128, KVBLK=64, 4 waves x 32 q-rows ----------------
__global__ __launch_bounds__(256, 2) void attn_kernel(
    const u16* __restrict__ Q, const u16* __restrict__ K,
    const u16* __restrict__ Vt, u16* __restrict__ ctx){
  __shared__ u16 buf[2][16384];  // per buffer: K [64][128] (8192 u16) then V [128][64]
  __shared__ u16 Psh[4*32*64];   // 16 KB: per-wave P [32 q][64 kv], XOR-swizzled
  int tid = threadIdx.x, w = tid >> 6, lane = tid & 63;
  int l15 = lane & 15, l4 = lane >> 4;
  // T1: XCD-aware remap. 512 blocks, 8 XCDs (wgid%8 = XCD): XCD k gets bh in [4k,4k+4)
  int lin = blockIdx.x;
  int virt = (lin & 7) * 64 + (lin >> 3);
  int qt = virt & 15, bh = virt >> 4;
  int b = bh >> 4, h = bh & 15;
  const u16* Qg = Q + (size_t)(b*2048 + qt*128) * 2048 + h*128;
  const u16* Kg = K + (size_t)(b*2048) * 2048 + h*128;
  const u16* Vg = Vt + (size_t)bh * 128 * 2048;

  // prologue: Q -> buf[1], kv-tile 0 -> buf[0]
  #pragma unroll
  for (int i=0; i<8; ++i){
    int e = (i*256 + tid) * 8;
    int r = e >> 7, cc = e & 127;
    gload16(Qg + (size_t)r*2048 + cc, (char*)buf[1] + i*4096 + w*1024);
  }
  #pragma unroll
  for (int i=0; i<4; ++i){
    int e = (i*256 + tid) * 8;
    int r = e >> 7, cc = e & 127;
    gload16(Kg + (size_t)r*2048 + cc, (char*)buf[0] + i*4096 + w*1024);
    int dd = e >> 6, c2 = e & 63;
    gload16(Vg + (size_t)dd*2048 + c2, (char*)buf[0] + 16384 + i*4096 + w*1024);
  }
  __syncthreads();   // drains vmcnt

  bf16x8 qf[2][4];   // Q rows (pre-scaled by log2e/sqrt(dk)); used as B operand
  #pragma unroll
  for (int mi=0; mi<2; mi++){
    int r = w*32 + mi*16 + l15;
    #pragma unroll
    for (int kb=0; kb<4; kb++){
      int cc = (kb*32 + l4*8) ^ ((r & 7) << 3);
      qf[mi][kb] = *(const bf16x8*)(buf[1] + r*128 + cc);
    }
  }
  __syncthreads();   // all waves done with Q region before it becomes buffer 1

  // O^T accumulator: ctxa[mi][nd] reg j -> d = nd*16 + l4*4 + j, q = mi*16 + l15
  f32x4 ctxa[2][8];
  #pragma unroll
  for (int mi=0; mi<2; mi++)
    #pragma unroll
    for (int nd=0; nd<8; nd++) ctxa[mi][nd] = (f32x4){0.f,0.f,0.f,0.f};
  float mrun[2] = {-3.0e38f, -3.0e38f};
  float lrun[2] = {0.f, 0.f};

  char* PwB = (char*)(Psh + w * (32*64));   // byte base of this wave's P tile
  int psw = (l15 & 7) << 4;                 // byte XOR swizzle for P (row = mi*16+l15)

  for (int t = 0; t < 32; ++t){
    int cur = t & 1;
    const u16* Kc = buf[cur];
    const u16* Vc = buf[cur] + 8192;
    // prefetch next kv tile into the other buffer (latency hides under compute)
    if (t + 1 < 32){
      int kvn = (t + 1) * 64;
      char* bn = (char*)buf[cur ^ 1];
      #pragma unroll
      for (int i=0; i<4; ++i){
        int e = (i*256 + tid) * 8;
        int r = e >> 7, cc = e & 127;
        gload16(Kg + (size_t)(kvn + r)*2048 + cc, bn + i*4096 + w*1024);
        int dd = e >> 6, c2 = e & 63;
        gload16(Vg + (size_t)dd*2048 + kvn + c2, bn + 16384 + i*4096 + w*1024);
      }
    }
    // S^T = mfma(K, Q): lane reg j of s[mi][ni]: kv = ni*16 + l4*4 + j, q = mi*16 + l15
    f32x4 s[2][4];
    #pragma unroll
    for (int mi=0; mi<2; mi++)
      #pragma unroll
      for (int ni=0; ni<4; ni++) s[mi][ni] = (f32x4){0.f,0.f,0.f,0.f};
    __builtin_amdgcn_s_setprio(1);
    #pragma unroll
    for (int kb=0; kb<4; kb++){
      #pragma unroll
      for (int ni=0; ni<4; ni++){
        int r = ni*16 + l15;
        int cc = (kb*32 + l4*8) ^ ((r & 7) << 3);
        bf16x8 kf = *(const bf16x8*)(Kc + r*128 + cc);
        s[0][ni] = __builtin_amdgcn_mfma_f32_16x16x32_bf16(kf, qf[0][kb], s[0][ni], 0, 0, 0);
        s[1][ni] = __builtin_amdgcn_mfma_f32_16x16x32_bf16(kf, qf[1][kb], s[1][ni], 0, 0, 0);
      }
    }
    __builtin_amdgcn_s_setprio(0);
    // in-lane tile max per q-row (16 values) + cross-l4 combine
    float pm[2];
    #pragma unroll
    for (int mi=0; mi<2; mi++){
      float v = s[mi][0][0];
      #pragma unroll
      for (int ni=0; ni<4; ni++)
        #pragma unroll
        for (int j=0; j<4; j++) v = fmaxf(v, s[mi][ni][j]);
      v = fmaxf(v, __shfl_xor(v, 16));
      v = fmaxf(v, __shfl_xor(v, 32));
      pm[mi] = v;
    }
    // T13 defer-max: rescale only when max grows beyond THR (exp2 domain)
    bool need = (pm[0] > mrun[0] + RESCALE_THR) || (pm[1] > mrun[1] + RESCALE_THR);
    if (__any(need)){
      #pragma unroll
      for (int mi=0; mi<2; mi++){
        float mnew = fmaxf(mrun[mi], pm[mi]);
        float cr = exp2f(mrun[mi] - mnew);
        lrun[mi] *= cr;
        mrun[mi] = mnew;
        #pragma unroll
        for (int nd=0; nd<8; nd++) ctxa[mi][nd] *= cr;
      }
    }
    // P = exp2(S - m), pack to bf16, ds_write_b64 (4 consecutive kv per write)
    #pragma unroll
    for (int mi=0; mi<2; mi++){
      float ps = 0.f;
      #pragma unroll
      for (int ni=0; ni<4; ni++){
        float p0 = exp2f(s[mi][ni][0] - mrun[mi]);
        float p1 = exp2f(s[mi][ni][1] - mrun[mi]);
        float p2 = exp2f(s[mi][ni][2] - mrun[mi]);
        float p3 = exp2f(s[mi][ni][3] - mrun[mi]);
        ps += (p0 + p1) + (p2 + p3);
        uint2 pk = {cvt_pk_bf16(p0, p1), cvt_pk_bf16(p2, p3)};
        *(uint2*)(PwB + (mi*16 + l15)*128 + ((ni*32 + l4*8) ^ psw)) = pk;
      }
      ps += __shfl_xor(ps, 16);
      ps += __shfl_xor(ps, 32);
      lrun[mi] += ps;
    }
    // PV (swapped): O^T += mfma(V^T, P); B-frag = P[q=l15(+16mi)][kv=l4*8..+8]
    bf16x8 pb[2][2];
    #pragma unroll
    for (int mi=0; mi<2; mi++)
      #pragma unroll
      for (int kvb=0; kvb<2; kvb++)
        pb[mi][kvb] = *(const bf16x8*)(PwB + (mi*16 + l15)*128 + ((kvb*64 + l4*16) ^ psw));
    __builtin_amdgcn_s_setprio(1);
    #pragma unroll
    for (int nd=0; nd<8; nd++){
      int dd = nd*16 + l15;
      int sw = (dd & 7) << 3;
      #pragma unroll
      for (int kvb=0; kvb<2; kvb++){
        bf16x8 vf = *(const bf16x8*)(Vc + dd*64 + ((kvb*32 + l4*8) ^ sw));
        ctxa[0][nd] = __builtin_amdgcn_mfma_f32_16x16x32_bf16(vf, pb[0][kvb], ctxa[0][nd], 0, 0, 0);
        ctxa[1][nd] = __builtin_amdgcn_mfma_f32_16x16x32_bf16(vf, pb[1][kvb], ctxa[1][nd], 0, 0, 0);
      }
    }
    __builtin_amdgcn_s_setprio(0);
    __syncthreads();   // implicit vmcnt(0): next buffer ready; all waves done with cur
  }
  // epilogue: normalize, transpose through per-wave LDS region, coalesced store
  char* OwB = (char*)buf[0] + w*8192;   // [32 q][128 d] bf16, XOR-swizzled
  #pragma unroll
  for (int mi=0; mi<2; mi++){
    float inv = 1.0f / lrun[mi];
    #pragma unroll
    for (int nd=0; nd<8; nd++){
      f32x4 c = ctxa[mi][nd] * inv;
      uint2 pk = {cvt_pk_bf16(c[0], c[1]), cvt_pk_bf16(c[2], c[3])};
      *(uint2*)(OwB + (mi*16 + l15)*256 + ((nd*32 + l4*8) ^ psw)) = pk;
    }
  }
  #pragma unroll
  for (int i=0; i<8; ++i){
    int row = i*4 + l4;          // 0..31
    int colb = l15*16;           // byte col 0..240
    uint4 v = *(const uint4*)(OwB + row*256 + (colb ^ ((row & 7) << 4)));
    int srow = qt*128 + w*32 + row;
    *(uint4*)(ctx + ((size_t)(b*2048 + srow))*2048 + h*128 + colb/2) = v;
  }
}

// ---------------- launcher ----------------
extern "C" void kernel_launch(void* const* d_in, const int* in_sizes, int n_in,
                              void* d_out, int out_size, void* d_ws, size_t ws_size,
                              hipStream_t stream){
  const float* x  = (const float*)d_in[0];
  const float* Wq = (const float*)d_in[1];  const float* bq = (const float*)d_in[2];
  const float* Aq = (const float*)d_in[3];  const float* Bq = (const float*)d_in[4];
  const float* Wk = (const float*)d_in[5];  const float* bk = (const float*)d_in[6];
  const float* Ak = (const float*)d_in[7];  const float* Bk = (const float*)d_in[8];
  const float* Wv = (const float*)d_in[9];  const float* bv = (const float*)d_in[10];
  const float* Av = (const float*)d_in[11]; const float* Bv = (const float*)d_in[12];
  const float* Wo = (const float*)d_in[13]; const float* bo = (const float*)d_in[14];
  const float* Ao = (const float*)d_in[15]; const float* Bo = (const float*)d_in[16];

  char* ws = (char*)d_ws;
  size_t off = 0;
  u16* xbf  = (u16*)(ws + off); off += (size_t)4096*2048*2;          // 16 MB
  u16* wqkv = (u16*)(ws + off); off += (size_t)3*2048*2048*2;        // 24 MB
  u16* wob  = (u16*)(ws + off); off += (size_t)2048*2048*2;          // 8 MB
  float* xa = (float*)(ws + off); off += (size_t)4*32768*4;          // 4 slabs [4096][8]
  u16* Qb  = (u16*)(ws + off); off += (size_t)4096*2048*2;
  u16* Kb  = (u16*)(ws + off); off += (size_t)4096*2048*2;
  u16* Vb  = (u16*)(ws + off); off += (size_t)4096*2048*2;           // later reused as ctx
  u16* Vtb = (u16*)(ws + off); off += (size_t)4096*2048*2;
  if (ws_size < off) return;   // insufficient scratch — bail (will fail validation loudly)

  cvt_w4<<<8192, 256, 0, stream>>>(Wq, Wk, Wv, Wo, wqkv, wob);
  lora_x_fused<<<1024, 256, 0, stream>>>(x, Aq, Ak, Av, xa, xbf);

  gemm_qkv<<<dim3(48,32), 256, 0, stream>>>(xbf, wqkv, bq, bk, bv, Bq, Bk, Bv, xa, Qb, Kb, Vb);

  transpose_v<<<dim3(32,64), 256, 0, stream>>>(Vb, Vtb);

  attn_kernel<<<512, 256, 0, stream>>>(Qb, Kb, Vtb, Vb);   // ctx -> Vb (V dead after transpose)

  lora_xa_bf16<<<1024, 256, 0, stream>>>(Vb, Ao, xa+98304);

  gemm_o<<<dim3(16,32), 256, 0, stream>>>(Vb, wob, bo, Bo, xa+98304, (float*)d_out);
}

// Round 6
// 354.979 us; speedup vs baseline: 1.2526x; 1.0063x over previous
//
#include <hip/hip_runtime.h>
#include <stdint.h>

typedef unsigned short u16;
typedef unsigned int   u32;
typedef __bf16  bf16x8 __attribute__((ext_vector_type(8)));
typedef float   f32x4  __attribute__((ext_vector_type(4)));

#define LORA_SCALE 2.0f
#define QSCALE 0.08838834764831845f   // 1/sqrt(128)
#define LOG2E  1.4426950408889634f
#define RESCALE_THR 8.0f

__device__ __forceinline__ u16 f2bf(float f){
  u32 u = __builtin_bit_cast(u32, f);
  u32 r = (u + 0x7fffu + ((u >> 16) & 1u)) >> 16;   // RNE
  return (u16)r;
}
__device__ __forceinline__ float bf2f(u16 v){
  return __builtin_bit_cast(float, ((u32)v) << 16);
}
// pack 2 f32 -> 2 bf16 in one VALU op (no builtin on gfx950; T12 recipe)
__device__ __forceinline__ u32 cvt_pk_bf16(float lo, float hi){
  u32 d;
  asm("v_cvt_pk_bf16_f32 %0, %1, %2" : "=v"(d) : "v"(lo), "v"(hi));
  return d;
}

typedef __attribute__((address_space(3))) u32 lds_u32_t;
typedef __attribute__((address_space(1))) const u32 g_u32_t;

// async global->LDS, 16B per lane; LDS dest = wave-uniform base + lane*16
__device__ __forceinline__ void gload16(const void* g, void* l){
  __builtin_amdgcn_global_load_lds((g_u32_t*)(unsigned long long)g,
                                   (lds_u32_t*)(u32)(unsigned long long)l,
                                   16, 0, 0);
}

// ---------------- 4x W fp32 -> bf16 convert, one launch ----------------
__global__ __launch_bounds__(256) void cvt_w4(const float* __restrict__ W0,
    const float* __restrict__ W1, const float* __restrict__ W2,
    const float* __restrict__ W3, u16* __restrict__ wqkv, u16* __restrict__ wo){
  int sel = blockIdx.x >> 11;
  int inner = blockIdx.x & 2047;
  const float* src = sel==0 ? W0 : sel==1 ? W1 : sel==2 ? W2 : W3;
  u16* dst = sel<3 ? (wqkv + (size_t)sel*4194304) : wo;
  int i = (inner*256 + threadIdx.x) * 8;
  float4 a = *(const float4*)(src + i);
  float4 b = *(const float4*)(src + i + 4);
  u16 o[8] = {f2bf(a.x),f2bf(a.y),f2bf(a.z),f2bf(a.w),
              f2bf(b.x),f2bf(b.y),f2bf(b.z),f2bf(b.w)};
  *(uint4*)(dst + i) = *(const uint4*)o;
}

// ---------------- fused: x fp32 -> xbf bf16  AND  xa[m][r] for 3 A's ----------------
__global__ __launch_bounds__(256) void lora_x_fused(const float* __restrict__ x,
    const float* __restrict__ A0, const float* __restrict__ A1, const float* __restrict__ A2,
    float* __restrict__ xout, u16* __restrict__ xbf){
  int w = threadIdx.x >> 6, lane = threadIdx.x & 63;
  int m = blockIdx.x * 4 + w;
  float acc[3][8];
  #pragma unroll
  for (int g=0; g<3; ++g)
    #pragma unroll
    for (int r=0; r<8; ++r) acc[g][r] = 0.f;
  const float* As[3] = {A0, A1, A2};
  #pragma unroll 1
  for (int it=0; it<8; ++it){
    int k = it*256 + lane*4;
    float4 xv = *(const float4*)(x + (size_t)m*2048 + k);
    u16 o[4] = {f2bf(xv.x), f2bf(xv.y), f2bf(xv.z), f2bf(xv.w)};
    *(uint2*)(xbf + (size_t)m*2048 + k) = *(const uint2*)o;
    #pragma unroll
    for (int g=0; g<3; ++g){
      const float* Ag = As[g];
      #pragma unroll
      for (int r=0; r<8; ++r){
        float4 av = *(const float4*)(Ag + r*2048 + k);
        acc[g][r] += xv.x*av.x + xv.y*av.y + xv.z*av.z + xv.w*av.w;
      }
    }
  }
  #pragma unroll
  for (int g=0; g<3; ++g)
    #pragma unroll
    for (int r=0; r<8; ++r){
      float v = acc[g][r];
      #pragma unroll
      for (int off=32; off; off>>=1) v += __shfl_xor(v, off);
      if (lane == 0) xout[g*32768 + m*8 + r] = v;
    }
}

// ---------------- LoRA stage 1 (ctx bf16 path) ----------------
__global__ __launch_bounds__(256) void lora_xa_bf16(const u16* __restrict__ xin,
    const float* __restrict__ A0, float* __restrict__ xout){
  int w = threadIdx.x >> 6, lane = threadIdx.x & 63;
  int m = blockIdx.x * 4 + w;
  float acc[8];
  #pragma unroll
  for (int r=0; r<8; ++r) acc[r] = 0.f;
  #pragma unroll 1
  for (int it=0; it<8; ++it){
    int k = it*256 + lane*4;
    ushort4 u = *(const ushort4*)(xin + (size_t)m*2048 + k);
    float4 xv = {bf2f(u.x), bf2f(u.y), bf2f(u.z), bf2f(u.w)};
    #pragma unroll
    for (int r=0; r<8; ++r){
      float4 av = *(const float4*)(A0 + r*2048 + k);
      acc[r] += xv.x*av.x + xv.y*av.y + xv.z*av.z + xv.w*av.w;
    }
  }
  #pragma unroll
  for (int r=0; r<8; ++r){
    float v = acc[r];
    #pragma unroll
    for (int off=32; off; off>>=1) v += __shfl_xor(v, off);
    if (lane == 0) xout[m*8 + r] = v;
  }
}

// ---------------- deep-pipelined GEMM core: 256x128 tile, 8 waves, BK=32 ----------------
// 4 LDS buffers (24KB each: A 256x32 @0, B 128x32 @16384). Stage tile T+3 while
// computing T; 2 phases per K-tile, 8 MFMA each; vmcnt(6) once per K-tile (never 0
// until the 2-iter tail). T2 swizzle: LDS row r, 16B-slot s holds global slot
// s ^ ((r>>1)&3); applied inverse on gload source, forward on ds_read.
__device__ __forceinline__ void gemm_core_256(
    const u16* __restrict__ Aptr,   // A + m0*2048  (256 rows)
    const u16* __restrict__ Wptr,   // W + n0g*2048 (128 rows)
    u16* lds, int tid, f32x4 acc[4][4]){
  const int Kd = 2048;
  int l = tid & 63, w = tid >> 6;
  int l15 = l & 15, l4 = l >> 4;
  int wm = w >> 1, wn = w & 1;                    // 4M x 2N waves
  // staging geometry: lane covers row w*16+(l>>2), inverse-swizzled col
  int srow = w*16 + (l >> 2);
  int scol = ((l & 3) ^ ((l >> 3) & 3)) * 8;
  const u16* asrc0 = Aptr + (size_t)srow * Kd + scol;
  const u16* asrc1 = asrc0 + (size_t)128 * Kd;
  const u16* bsrc  = Wptr + (size_t)srow * Kd + scol;
  char* L = (char*)lds;
  int wb = w * 1024;

  // ds_read addressing (swizzled): byte = buf + row*64 + ((l4 ^ ((l15>>1)&3))<<4)
  int rsw = ((l4 ^ ((l15 >> 1) & 3)) << 4);
  int abase = (wm*64 + l15)*64 + rsw;             // + mr*1024 + buf
  int bbase = 16384 + (wn*64 + l15)*64 + rsw;     // + nr*1024 + buf

  #define STAGE_A(t) { int bb_ = ((t)&3)*24576; \
      gload16(asrc0 + (t)*32, L + bb_ + wb); \
      gload16(asrc1 + (t)*32, L + bb_ + 8192 + wb); }
  #define STAGE_B(t) { int bb_ = ((t)&3)*24576; \
      gload16(bsrc + (t)*32, L + bb_ + 16384 + wb); }

  STAGE_A(0); STAGE_B(0); STAGE_A(1); STAGE_B(1); STAGE_A(2); STAGE_B(2);
  asm volatile("s_waitcnt vmcnt(6)" ::: "memory");   // tile 0 resident
  __builtin_amdgcn_s_barrier();

  #pragma unroll 1
  for (int t = 0; t < 64; ++t){
    int bb = (t & 3) * 24576;
    // ---- phase 0: A rows 0-1, all B cols; stage A(t+3) ----
    bf16x8 bf[4], af0, af1;
    af0 = *(const bf16x8*)(L + bb + abase);
    af1 = *(const bf16x8*)(L + bb + abase + 1024);
    #pragma unroll
    for (int nr=0; nr<4; ++nr) bf[nr] = *(const bf16x8*)(L + bb + bbase + nr*1024);
    if (t < 61) STAGE_A(t+3);
    __builtin_amdgcn_s_barrier();
    __builtin_amdgcn_s_setprio(1);
    #pragma unroll
    for (int nr=0; nr<4; ++nr){
      acc[0][nr] = __builtin_amdgcn_mfma_f32_16x16x32_bf16(af0, bf[nr], acc[0][nr], 0, 0, 0);
      acc[1][nr] = __builtin_amdgcn_mfma_f32_16x16x32_bf16(af1, bf[nr], acc[1][nr], 0, 0, 0);
    }
    __builtin_amdgcn_s_setprio(0);
    __builtin_amdgcn_s_barrier();
    // ---- phase 1: A rows 2-3 (reuse bf); stage B(t+3); counted vmcnt ----
    af0 = *(const bf16x8*)(L + bb + abase + 2048);
    af1 = *(const bf16x8*)(L + bb + abase + 3072);
    if (t < 61){
      STAGE_B(t+3);
      asm volatile("s_waitcnt vmcnt(6)" ::: "memory");   // tile t+1 resident; t+2,t+3 in flight
    } else if (t == 61){
      asm volatile("s_waitcnt vmcnt(3)" ::: "memory");
    } else if (t == 62){
      asm volatile("s_waitcnt vmcnt(0)" ::: "memory");
    }
    __builtin_amdgcn_s_barrier();
    __builtin_amdgcn_s_setprio(1);
    #pragma unroll
    for (int nr=0; nr<4; ++nr){
      acc[2][nr] = __builtin_amdgcn_mfma_f32_16x16x32_bf16(af0, bf[nr], acc[2][nr], 0, 0, 0);
      acc[3][nr] = __builtin_amdgcn_mfma_f32_16x16x32_bf16(af1, bf[nr], acc[3][nr], 0, 0, 0);
    }
    __builtin_amdgcn_s_setprio(0);
    __builtin_amdgcn_s_barrier();
  }
  #undef STAGE_A
  #undef STAGE_B
}

// ---------------- fused QKV GEMM (256x128 tiles, 768 blocks) ----------------
__global__ __launch_bounds__(512, 2) void gemm_qkv(
    const u16* __restrict__ A, const u16* __restrict__ W,
    const float* __restrict__ bq, const float* __restrict__ bk, const float* __restrict__ bv,
    const float* __restrict__ lBq, const float* __restrict__ lBk, const float* __restrict__ lBv,
    const float* __restrict__ xa, u16* __restrict__ Qb, u16* __restrict__ Kb, u16* __restrict__ Vb){
  __shared__ u16 lds[49152];   // 96 KB: 4 bufs x 24KB
  int tid = threadIdx.x;
  int l = tid & 63, w = tid >> 6;
  int l15 = l & 15, l4 = l >> 4;
  int wm = w >> 1, wn = w & 1;
  // XCD-aware bijective remap (768 % 8 == 0)
  int bid = blockIdx.x;
  int virt = (bid & 7) * 96 + (bid >> 3);
  int mt = virt & 15, nt = virt >> 4;            // nt 0..47
  int m0 = mt * 256, n0g = nt * 128;
  int which = nt >> 4;                            // 0=q 1=k 2=v
  int n0 = (nt & 15) * 128;
  const float* bias = which==0 ? bq : which==1 ? bk : bv;
  const float* lB   = which==0 ? lBq : which==1 ? lBk : lBv;
  const float* xs   = xa + which*32768;
  u16* outp         = which==0 ? Qb : which==1 ? Kb : Vb;
  int swz = (which <= 1);
  float oscale = (which == 0) ? QSCALE*LOG2E : 1.0f;

  f32x4 acc[4][4];
  #pragma unroll
  for (int mr=0; mr<4; mr++)
    #pragma unroll
    for (int nr=0; nr<4; nr++) acc[mr][nr] = (f32x4){0.f,0.f,0.f,0.f};

  gemm_core_256(A + (size_t)m0*2048, W + (size_t)n0g*2048, lds, tid, acc);

  float bvv[4]; float4 lb0[4], lb1[4];
  #pragma unroll
  for (int nr=0; nr<4; nr++){
    int col = n0 + wn*64 + nr*16 + l15;
    bvv[nr] = bias[col];
    lb0[nr] = *(const float4*)(lB + col*8);
    lb1[nr] = *(const float4*)(lB + col*8 + 4);
  }
  #pragma unroll
  for (int mr=0; mr<4; mr++)
    #pragma unroll
    for (int j=0; j<4; j++){
      int r = m0 + wm*64 + mr*16 + l4*4 + j;
      float4 xv0 = *(const float4*)(xs + (size_t)r*8);
      float4 xv1 = *(const float4*)(xs + (size_t)r*8 + 4);
      #pragma unroll
      for (int nr=0; nr<4; nr++){
        int col = n0 + wn*64 + nr*16 + l15;
        float v = acc[mr][nr][j] + bvv[nr] + LORA_SCALE * (
            xv0.x*lb0[nr].x + xv0.y*lb0[nr].y + xv0.z*lb0[nr].z + xv0.w*lb0[nr].w +
            xv1.x*lb1[nr].x + xv1.y*lb1[nr].y + xv1.z*lb1[nr].z + xv1.w*lb1[nr].w);
        v *= oscale;
        int cs = swz ? (col ^ ((r & 7) << 3)) : col;
        outp[(size_t)r*2048 + cs] = f2bf(v);
      }
    }
}

// ---------------- O projection GEMM (256x128 tiles, 256 blocks, fp32 out) ----------------
__global__ __launch_bounds__(512, 2) void gemm_o(
    const u16* __restrict__ A, const u16* __restrict__ W,
    const float* __restrict__ bias, const float* __restrict__ lB,
    const float* __restrict__ xa, float* __restrict__ outp){
  __shared__ u16 lds[49152];   // 96 KB
  int tid = threadIdx.x;
  int l = tid & 63, w = tid >> 6;
  int l15 = l & 15, l4 = l >> 4;
  int wm = w >> 1, wn = w & 1;
  int bid = blockIdx.x;
  int virt = (bid & 7) * 32 + (bid >> 3);        // 256 % 8 == 0, bijective
  int mt = virt & 15, nt = virt >> 4;            // nt 0..15
  int m0 = mt * 256, n0 = nt * 128;

  f32x4 acc[4][4];
  #pragma unroll
  for (int mr=0; mr<4; mr++)
    #pragma unroll
    for (int nr=0; nr<4; nr++) acc[mr][nr] = (f32x4){0.f,0.f,0.f,0.f};

  gemm_core_256(A + (size_t)m0*2048, W + (size_t)n0*2048, lds, tid, acc);

  float bv[4]; float4 lb0[4], lb1[4];
  #pragma unroll
  for (int nr=0; nr<4; nr++){
    int col = n0 + wn*64 + nr*16 + l15;
    bv[nr] = bias[col];
    lb0[nr] = *(const float4*)(lB + col*8);
    lb1[nr] = *(const float4*)(lB + col*8 + 4);
  }
  #pragma unroll
  for (int mr=0; mr<4; mr++)
    #pragma unroll
    for (int j=0; j<4; j++){
      int r = m0 + wm*64 + mr*16 + l4*4 + j;
      float4 xv0 = *(const float4*)(xa + (size_t)r*8);
      float4 xv1 = *(const float4*)(xa + (size_t)r*8 + 4);
      #pragma unroll
      for (int nr=0; nr<4; nr++){
        int col = n0 + wn*64 + nr*16 + l15;
        float v = acc[mr][nr][j] + bv[nr] + LORA_SCALE * (
            xv0.x*lb0[nr].x + xv0.y*lb0[nr].y + xv0.z*lb0[nr].z + xv0.w*lb0[nr].w +
            xv1.x*lb1[nr].x + xv1.y*lb1[nr].y + xv1.z*lb1[nr].z + xv1.w*lb1[nr].w);
        outp[(size_t)r*2048 + col] = v;
      }
    }
}

// ---------------- V transpose: V[4096][2048] -> Vt[bh][d][s] (kv-swizzled) ----------------
__global__ __launch_bounds__(256) void transpose_v(const u16* __restrict__ V,
                                                   u16* __restrict__ Vt){
  __shared__ u16 tile[64*80];
  int tid = threadIdx.x;
  int f0 = blockIdx.x * 64, m0 = blockIdx.y * 64;
  int i = tid >> 2, j0 = (tid & 3) * 16;
  #pragma unroll
  for (int kk=0; kk<16; kk+=8){
    uint4 u = *(const uint4*)(V + (size_t)(m0 + i)*2048 + f0 + j0 + kk);
    *(uint4*)(tile + i*80 + j0 + kk) = u;
  }
  __syncthreads();
  int j = tid >> 2, i0 = (tid & 3) * 16;
  int b = m0 >> 11, s0 = m0 & 2047;
  int h = f0 >> 7, d = (f0 & 127) + j;
  int c = (d & 7) << 3;
  size_t obase = ((size_t)((b*16 + h)*128 + d)) * 2048 + s0;
  #pragma unroll
  for (int kk=0; kk<16; kk+=8){
    u16 v8[8];
    #pragma unroll
    for (int u2=0; u2<8; ++u2) v8[u2] = tile[(i0+kk+u2)*80 + j];
    *(uint4*)(Vt + obase + ((i0+kk) ^ c)) = *(const uint4*)v8;   // (x^c)+u == (x+u)^c, c%8==0
  }
}

// ---------------- flash attention: QBLK=128, KVBLK=64, 4 waves x 32 q-rows ----------------
__global__ __launch_bounds__(256, 2) void attn_kernel(
    const u16* __restrict__ Q, const u16* __restrict__ K,
    const u16* __restrict__ Vt, u16* __restrict__ ctx){
  __shared__ u16 buf[2][16384];  // per buffer: K [64][128] (8192 u16) then V [128][64]
  __shared__ u16 Psh[4*32*64];   // 16 KB: per-wave P [32 q][64 kv], XOR-swizzled
  int tid = threadIdx.x, w = tid >> 6, lane = tid & 63;
  int l15 = lane & 15, l4 = lane >> 4;
  // T1: XCD-aware remap. 512 blocks, 8 XCDs (wgid%8 = XCD): XCD k gets bh in [4k,4k+4)
  int lin = blockIdx.x;
  int virt = (lin & 7) * 64 + (lin >> 3);
  int qt = virt & 15, bh = virt >> 4;
  int b = bh >> 4, h = bh & 15;
  const u16* Qg = Q + (size_t)(b*2048 + qt*128) * 2048 + h*128;
  const u16* Kg = K + (size_t)(b*2048) * 2048 + h*128;
  const u16* Vg = Vt + (size_t)bh * 128 * 2048;

  // prologue: Q -> buf[1], kv-tile 0 -> buf[0]
  #pragma unroll
  for (int i=0; i<8; ++i){
    int e = (i*256 + tid) * 8;
    int r = e >> 7, cc = e & 127;
    gload16(Qg + (size_t)r*2048 + cc, (char*)buf[1] + i*4096 + w*1024);
  }
  #pragma unroll
  for (int i=0; i<4; ++i){
    int e = (i*256 + tid) * 8;
    int r = e >> 7, cc = e & 127;
    gload16(Kg + (size_t)r*2048 + cc, (char*)buf[0] + i*4096 + w*1024);
    int dd = e >> 6, c2 = e & 63;
    gload16(Vg + (size_t)dd*2048 + c2, (char*)buf[0] + 16384 + i*4096 + w*1024);
  }
  __syncthreads();   // drains vmcnt

  bf16x8 qf[2][4];   // Q rows (pre-scaled by log2e/sqrt(dk)); used as B operand
  #pragma unroll
  for (int mi=0; mi<2; mi++){
    int r = w*32 + mi*16 + l15;
    #pragma unroll
    for (int kb=0; kb<4; kb++){
      int cc = (kb*32 + l4*8) ^ ((r & 7) << 3);
      qf[mi][kb] = *(const bf16x8*)(buf[1] + r*128 + cc);
    }
  }
  __syncthreads();   // all waves done with Q region before it becomes buffer 1

  // O^T accumulator: ctxa[mi][nd] reg j -> d = nd*16 + l4*4 + j, q = mi*16 + l15
  f32x4 ctxa[2][8];
  #pragma unroll
  for (int mi=0; mi<2; mi++)
    #pragma unroll
    for (int nd=0; nd<8; nd++) ctxa[mi][nd] = (f32x4){0.f,0.f,0.f,0.f};
  float mrun[2] = {-3.0e38f, -3.0e38f};
  float lrun[2] = {0.f, 0.f};

  char* PwB = (char*)(Psh + w * (32*64));   // byte base of this wave's P tile
  int psw = (l15 & 7) << 4;                 // byte XOR swizzle for P (row = mi*16+l15)

  for (int t = 0; t < 32; ++t){
    int cur = t & 1;
    const u16* Kc = buf[cur];
    const u16* Vc = buf[cur] + 8192;
    // prefetch next kv tile into the other buffer (latency hides under compute)
    if (t + 1 < 32){
      int kvn = (t + 1) * 64;
      char* bn = (char*)buf[cur ^ 1];
      #pragma unroll
      for (int i=0; i<4; ++i){
        int e = (i*256 + tid) * 8;
        int r = e >> 7, cc = e & 127;
        gload16(Kg + (size_t)(kvn + r)*2048 + cc, bn + i*4096 + w*1024);
        int dd = e >> 6, c2 = e & 63;
        gload16(Vg + (size_t)dd*2048 + kvn + c2, bn + 16384 + i*4096 + w*1024);
      }
    }
    // S^T = mfma(K, Q): lane reg j of s[mi][ni]: kv = ni*16 + l4*4 + j, q = mi*16 + l15
    f32x4 s[2][4];
    #pragma unroll
    for (int mi=0; mi<2; mi++)
      #pragma unroll
      for (int ni=0; ni<4; ni++) s[mi][ni] = (f32x4){0.f,0.f,0.f,0.f};
    __builtin_amdgcn_s_setprio(1);
    #pragma unroll
    for (int kb=0; kb<4; kb++){
      #pragma unroll
      for (int ni=0; ni<4; ni++){
        int r = ni*16 + l15;
        int cc = (kb*32 + l4*8) ^ ((r & 7) << 3);
        bf16x8 kf = *(const bf16x8*)(Kc + r*128 + cc);
        s[0][ni] = __builtin_amdgcn_mfma_f32_16x16x32_bf16(kf, qf[0][kb], s[0][ni], 0, 0, 0);
        s[1][ni] = __builtin_amdgcn_mfma_f32_16x16x32_bf16(kf, qf[1][kb], s[1][ni], 0, 0, 0);
      }
    }
    __builtin_amdgcn_s_setprio(0);
    // in-lane tile max per q-row (16 values) + cross-l4 combine
    float pm[2];
    #pragma unroll
    for (int mi=0; mi<2; mi++){
      float v = s[mi][0][0];
      #pragma unroll
      for (int ni=0; ni<4; ni++)
        #pragma unroll
        for (int j=0; j<4; j++) v = fmaxf(v, s[mi][ni][j]);
      v = fmaxf(v, __shfl_xor(v, 16));
      v = fmaxf(v, __shfl_xor(v, 32));
      pm[mi] = v;
    }
    // T13 defer-max: rescale only when max grows beyond THR (exp2 domain)
    bool need = (pm[0] > mrun[0] + RESCALE_THR) || (pm[1] > mrun[1] + RESCALE_THR);
    if (__any(need)){
      #pragma unroll
      for (int mi=0; mi<2; mi++){
        float mnew = fmaxf(mrun[mi], pm[mi]);
        float cr = exp2f(mrun[mi] - mnew);
        lrun[mi] *= cr;
        mrun[mi] = mnew;
        #pragma unroll
        for (int nd=0; nd<8; nd++) ctxa[mi][nd] *= cr;
      }
    }
    // P = exp2(S - m), pack to bf16, ds_write_b64 (4 consecutive kv per write)
    #pragma unroll
    for (int mi=0; mi<2; mi++){
      float ps = 0.f;
      #pragma unroll
      for (int ni=0; ni<4; ni++){
        float p0 = exp2f(s[mi][ni][0] - mrun[mi]);
        float p1 = exp2f(s[mi][ni][1] - mrun[mi]);
        float p2 = exp2f(s[mi][ni][2] - mrun[mi]);
        float p3 = exp2f(s[mi][ni][3] - mrun[mi]);
        ps += (p0 + p1) + (p2 + p3);
        uint2 pk = {cvt_pk_bf16(p0, p1), cvt_pk_bf16(p2, p3)};
        *(uint2*)(PwB + (mi*16 + l15)*128 + ((ni*32 + l4*8) ^ psw)) = pk;
      }
      ps += __shfl_xor(ps, 16);
      ps += __shfl_xor(ps, 32);
      lrun[mi] += ps;
    }
    // PV (swapped): O^T += mfma(V^T, P); B-frag = P[q=l15(+16mi)][kv=l4*8..+8]
    bf16x8 pb[2][2];
    #pragma unroll
    for (int mi=0; mi<2; mi++)
      #pragma unroll
      for (int kvb=0; kvb<2; kvb++)
        pb[mi][kvb] = *(const bf16x8*)(PwB + (mi*16 + l15)*128 + ((kvb*64 + l4*16) ^ psw));
    __builtin_amdgcn_s_setprio(1);
    #pragma unroll
    for (int nd=0; nd<8; nd++){
      int dd = nd*16 + l15;
      int sw = (dd & 7) << 3;
      #pragma unroll
      for (int kvb=0; kvb<2; kvb++){
        bf16x8 vf = *(const bf16x8*)(Vc + dd*64 + ((kvb*32 + l4*8) ^ sw));
        ctxa[0][nd] = __builtin_amdgcn_mfma_f32_16x16x32_bf16(vf, pb[0][kvb], ctxa[0][nd], 0, 0, 0);
        ctxa[1][nd] = __builtin_amdgcn_mfma_f32_16x16x32_bf16(vf, pb[1][kvb], ctxa[1][nd], 0, 0, 0);
      }
    }
    __builtin_amdgcn_s_setprio(0);
    __syncthreads();   // implicit vmcnt(0): next buffer ready; all waves done with cur
  }
  // epilogue: normalize, transpose through per-wave LDS region, coalesced store
  char* OwB = (char*)buf[0] + w*8192;   // [32 q][128 d] bf16, XOR-swizzled
  #pragma unroll
  for (int mi=0; mi<2; mi++){
    float inv = 1.0f / lrun[mi];
    #pragma unroll
    for (int nd=0; nd<8; nd++){
      f32x4 c = ctxa[mi][nd] * inv;
      uint2 pk = {cvt_pk_bf16(c[0], c[1]), cvt_pk_bf16(c[2], c[3])};
      *(uint2*)(OwB + (mi*16 + l15)*256 + ((nd*32 + l4*8) ^ psw)) = pk;
    }
  }
  #pragma unroll
  for (int i=0; i<8; ++i){
    int row = i*4 + l4;          // 0..31
    int colb = l15*16;           // byte col 0..240
    uint4 v = *(const uint4*)(OwB + row*256 + (colb ^ ((row & 7) << 4)));
    int srow = qt*128 + w*32 + row;
    *(uint4*)(ctx + ((size_t)(b*2048 + srow))*2048 + h*128 + colb/2) = v;
  }
}

// ---------------- launcher ----------------
extern "C" void kernel_launch(void* const* d_in, const int* in_sizes, int n_in,
                              void* d_out, int out_size, void* d_ws, size_t ws_size,
                              hipStream_t stream){
  const float* x  = (const float*)d_in[0];
  const float* Wq = (const float*)d_in[1];  const float* bq = (const float*)d_in[2];
  const float* Aq = (const float*)d_in[3];  const float* Bq = (const float*)d_in[4];
  const float* Wk = (const float*)d_in[5];  const float* bk = (const float*)d_in[6];
  const float* Ak = (const float*)d_in[7];  const float* Bk = (const float*)d_in[8];
  const float* Wv = (const float*)d_in[9];  const float* bv = (const float*)d_in[10];
  const float* Av = (const float*)d_in[11]; const float* Bv = (const float*)d_in[12];
  const float* Wo = (const float*)d_in[13]; const float* bo = (const float*)d_in[14];
  const float* Ao = (const float*)d_in[15]; const float* Bo = (const float*)d_in[16];

  char* ws = (char*)d_ws;
  size_t off = 0;
  u16* xbf  = (u16*)(ws + off); off += (size_t)4096*2048*2;          // 16 MB
  u16* wqkv = (u16*)(ws + off); off += (size_t)3*2048*2048*2;        // 24 MB
  u16* wob  = (u16*)(ws + off); off += (size_t)2048*2048*2;          // 8 MB
  float* xa = (float*)(ws + off); off += (size_t)4*32768*4;          // 4 slabs [4096][8]
  u16* Qb  = (u16*)(ws + off); off += (size_t)4096*2048*2;
  u16* Kb  = (u16*)(ws + off); off += (size_t)4096*2048*2;
  u16* Vb  = (u16*)(ws + off); off += (size_t)4096*2048*2;           // later reused as ctx
  u16* Vtb = (u16*)(ws + off); off += (size_t)4096*2048*2;
  if (ws_size < off) return;   // insufficient scratch — bail (will fail validation loudly)

  cvt_w4<<<8192, 256, 0, stream>>>(Wq, Wk, Wv, Wo, wqkv, wob);
  lora_x_fused<<<1024, 256, 0, stream>>>(x, Aq, Ak, Av, xa, xbf);

  gemm_qkv<<<768, 512, 0, stream>>>(xbf, wqkv, bq, bk, bv, Bq, Bk, Bv, xa, Qb, Kb, Vb);

  transpose_v<<<dim3(32,64), 256, 0, stream>>>(Vb, Vtb);

  attn_kernel<<<512, 256, 0, stream>>>(Qb, Kb, Vtb, Vb);   // ctx -> Vb (V dead after transpose)

  lora_xa_bf16<<<1024, 256, 0, stream>>>(Vb, Ao, xa+98304);

  gemm_o<<<256, 512, 0, stream>>>(Vb, wob, bo, Bo, xa+98304, (float*)d_out);
}

// Round 7
// 339.935 us; speedup vs baseline: 1.3080x; 1.0443x over previous
//
#include <hip/hip_runtime.h>
#include <stdint.h>

typedef unsigned short u16;
typedef unsigned int   u32;
typedef __bf16  bf16x8 __attribute__((ext_vector_type(8)));
typedef float   f32x4  __attribute__((ext_vector_type(4)));

#define LORA_SCALE 2.0f
#define QSCALE 0.08838834764831845f   // 1/sqrt(128)
#define LOG2E  1.4426950408889634f
#define RESCALE_THR 8.0f

__device__ __forceinline__ u16 f2bf(float f){
  u32 u = __builtin_bit_cast(u32, f);
  u32 r = (u + 0x7fffu + ((u >> 16) & 1u)) >> 16;   // RNE
  return (u16)r;
}
__device__ __forceinline__ float bf2f(u16 v){
  return __builtin_bit_cast(float, ((u32)v) << 16);
}
// pack 2 f32 -> 2 bf16 in one VALU op (no builtin on gfx950; T12 recipe)
__device__ __forceinline__ u32 cvt_pk_bf16(float lo, float hi){
  u32 d;
  asm("v_cvt_pk_bf16_f32 %0, %1, %2" : "=v"(d) : "v"(lo), "v"(hi));
  return d;
}

typedef __attribute__((address_space(3))) u32 lds_u32_t;
typedef __attribute__((address_space(1))) const u32 g_u32_t;

// async global->LDS, 16B per lane; LDS dest = wave-uniform base + lane*16
__device__ __forceinline__ void gload16(const void* g, void* l){
  __builtin_amdgcn_global_load_lds((g_u32_t*)(unsigned long long)g,
                                   (lds_u32_t*)(u32)(unsigned long long)l,
                                   16, 0, 0);
}

// ---------------- 4x W fp32 -> bf16 convert, one launch ----------------
__global__ __launch_bounds__(256) void cvt_w4(const float* __restrict__ W0,
    const float* __restrict__ W1, const float* __restrict__ W2,
    const float* __restrict__ W3, u16* __restrict__ wqkv, u16* __restrict__ wo){
  int sel = blockIdx.x >> 11;
  int inner = blockIdx.x & 2047;
  const float* src = sel==0 ? W0 : sel==1 ? W1 : sel==2 ? W2 : W3;
  u16* dst = sel<3 ? (wqkv + (size_t)sel*4194304) : wo;
  int i = (inner*256 + threadIdx.x) * 8;
  float4 a = *(const float4*)(src + i);
  float4 b = *(const float4*)(src + i + 4);
  u16 o[8] = {f2bf(a.x),f2bf(a.y),f2bf(a.z),f2bf(a.w),
              f2bf(b.x),f2bf(b.y),f2bf(b.z),f2bf(b.w)};
  *(uint4*)(dst + i) = *(const uint4*)o;
}

// ---------------- fused: x fp32 -> xbf bf16  AND  xa[m][r] for 3 A's ----------------
__global__ __launch_bounds__(256) void lora_x_fused(const float* __restrict__ x,
    const float* __restrict__ A0, const float* __restrict__ A1, const float* __restrict__ A2,
    float* __restrict__ xout, u16* __restrict__ xbf){
  int w = threadIdx.x >> 6, lane = threadIdx.x & 63;
  int m = blockIdx.x * 4 + w;
  float acc[3][8];
  #pragma unroll
  for (int g=0; g<3; ++g)
    #pragma unroll
    for (int r=0; r<8; ++r) acc[g][r] = 0.f;
  const float* As[3] = {A0, A1, A2};
  #pragma unroll 1
  for (int it=0; it<8; ++it){
    int k = it*256 + lane*4;
    float4 xv = *(const float4*)(x + (size_t)m*2048 + k);
    u16 o[4] = {f2bf(xv.x), f2bf(xv.y), f2bf(xv.z), f2bf(xv.w)};
    *(uint2*)(xbf + (size_t)m*2048 + k) = *(const uint2*)o;
    #pragma unroll
    for (int g=0; g<3; ++g){
      const float* Ag = As[g];
      #pragma unroll
      for (int r=0; r<8; ++r){
        float4 av = *(const float4*)(Ag + r*2048 + k);
        acc[g][r] += xv.x*av.x + xv.y*av.y + xv.z*av.z + xv.w*av.w;
      }
    }
  }
  #pragma unroll
  for (int g=0; g<3; ++g)
    #pragma unroll
    for (int r=0; r<8; ++r){
      float v = acc[g][r];
      #pragma unroll
      for (int off=32; off; off>>=1) v += __shfl_xor(v, off);
      if (lane == 0) xout[g*32768 + m*8 + r] = v;
    }
}

// ---------------- LoRA stage 1 (ctx bf16 path) ----------------
__global__ __launch_bounds__(256) void lora_xa_bf16(const u16* __restrict__ xin,
    const float* __restrict__ A0, float* __restrict__ xout){
  int w = threadIdx.x >> 6, lane = threadIdx.x & 63;
  int m = blockIdx.x * 4 + w;
  float acc[8];
  #pragma unroll
  for (int r=0; r<8; ++r) acc[r] = 0.f;
  #pragma unroll 1
  for (int it=0; it<8; ++it){
    int k = it*256 + lane*4;
    ushort4 u = *(const ushort4*)(xin + (size_t)m*2048 + k);
    float4 xv = {bf2f(u.x), bf2f(u.y), bf2f(u.z), bf2f(u.w)};
    #pragma unroll
    for (int r=0; r<8; ++r){
      float4 av = *(const float4*)(A0 + r*2048 + k);
      acc[r] += xv.x*av.x + xv.y*av.y + xv.z*av.z + xv.w*av.w;
    }
  }
  #pragma unroll
  for (int r=0; r<8; ++r){
    float v = acc[r];
    #pragma unroll
    for (int off=32; off; off>>=1) v += __shfl_xor(v, off);
    if (lane == 0) xout[m*8 + r] = v;
  }
}

// ---------------- GEMM core v7: BM=256 BN=128 BK=32, 4 waves 2Mx2N, per-wave 128x64 ----------------
// Tri-buffered LDS (3 x 24KB: A 256x32 @0, B 128x32 @16384). Stage K-step t+2 while
// computing t; vmcnt(6) once per K-step (6 = one stage-set in flight); drain at t=62.
// 2 phases/K-step x 16 MFMA; B-frags read once, reused in both phases.
// T2 swizzle (verified 0-conflict): LDS 16B-slot s at row r holds global slot s^((r>>1)&3).
__device__ __forceinline__ void gemm_core_v7(
    const u16* __restrict__ Aptr,   // + m0*2048 (256 rows)
    const u16* __restrict__ Wptr,   // + n0g*2048 (128 rows)
    u16* lds, int tid, f32x4 acc[8][4]){
  const int Kd = 2048;
  int l = tid & 63, w = tid >> 6;
  int l15 = l & 15, l4 = l >> 4;
  int wm = w >> 1, wn = w & 1;
  char* L = (char*)lds;
  int wb = w * 1024;
  // staging sources: 4 A-chunks + 2 B-chunks per thread, inverse-swizzled col
  const u16* asrc[4]; const u16* bsrc[2];
  #pragma unroll
  for (int i=0;i<4;i++){ int row=(i*4+w)*16+(l>>2); int sc=((l&3)^((row>>1)&3))<<3;
    asrc[i] = Aptr + (size_t)row*Kd + sc; }
  #pragma unroll
  for (int i=0;i<2;i++){ int row=(i*4+w)*16+(l>>2); int sc=((l&3)^((row>>1)&3))<<3;
    bsrc[i] = Wptr + (size_t)row*Kd + sc; }
  // ds_read byte offsets within a buffer (swizzled)
  int aoff[8], boff[4];
  #pragma unroll
  for (int mr=0;mr<8;mr++){ int ra=wm*128+mr*16+l15; aoff[mr]=ra*64+((l4^((ra>>1)&3))<<4); }
  #pragma unroll
  for (int nr=0;nr<4;nr++){ int rb=wn*64+nr*16+l15; boff[nr]=16384+rb*64+((l4^((rb>>1)&3))<<4); }

  auto STG = [&](int kt, int sbase){
    char* D = L + sbase;
    gload16(asrc[0]+kt, D +        wb);
    gload16(asrc[1]+kt, D +  4096+ wb);
    gload16(asrc[2]+kt, D +  8192+ wb);
    gload16(asrc[3]+kt, D + 12288+ wb);
    gload16(bsrc[0]+kt, D + 16384+ wb);
    gload16(bsrc[1]+kt, D + 20480+ wb);
  };

  STG(0, 0); STG(32, 24576);
  asm volatile("s_waitcnt vmcnt(6)" ::: "memory");   // K-step 0 resident
  __builtin_amdgcn_s_barrier();

  int bb = 0, sb = 49152, kt2 = 64;
  #pragma unroll 1
  for (int t = 0; t < 64; ++t){
    // ---- phase 0: A-frags 0-3 + all B-frags; issue stage(t+2) ----
    bf16x8 af[4], bf[4];
    #pragma unroll
    for (int mr=0;mr<4;mr++) af[mr] = *(const bf16x8*)(L + bb + aoff[mr]);
    #pragma unroll
    for (int nr=0;nr<4;nr++) bf[nr] = *(const bf16x8*)(L + bb + boff[nr]);
    if (t < 62) STG(kt2, sb);
    __builtin_amdgcn_s_barrier();
    __builtin_amdgcn_s_setprio(1);
    #pragma unroll
    for (int mr=0;mr<4;mr++)
      #pragma unroll
      for (int nr=0;nr<4;nr++)
        acc[mr][nr] = __builtin_amdgcn_mfma_f32_16x16x32_bf16(af[mr], bf[nr], acc[mr][nr], 0,0,0);
    __builtin_amdgcn_s_setprio(0);
    __builtin_amdgcn_s_barrier();
    // ---- phase 1: A-frags 4-7 (reuse B); counted vmcnt ----
    bf16x8 ag[4];
    #pragma unroll
    for (int mr=0;mr<4;mr++) ag[mr] = *(const bf16x8*)(L + bb + aoff[mr+4]);
    if (t < 62)       asm volatile("s_waitcnt vmcnt(6)" ::: "memory");   // t+1 resident
    else if (t == 62) asm volatile("s_waitcnt vmcnt(0)" ::: "memory");   // last resident
    __builtin_amdgcn_s_barrier();
    __builtin_amdgcn_s_setprio(1);
    #pragma unroll
    for (int mr=0;mr<4;mr++)
      #pragma unroll
      for (int nr=0;nr<4;nr++)
        acc[mr+4][nr] = __builtin_amdgcn_mfma_f32_16x16x32_bf16(ag[mr], bf[nr], acc[mr+4][nr], 0,0,0);
    __builtin_amdgcn_s_setprio(0);
    __builtin_amdgcn_s_barrier();
    bb = (bb == 49152) ? 0 : bb + 24576;
    sb = (sb == 49152) ? 0 : sb + 24576;
    kt2 += 32;
  }
}

// ---------------- fused QKV GEMM (256x128 tiles, 768 blocks, 4 waves) ----------------
__global__ __launch_bounds__(256, 2) void gemm_qkv(
    const u16* __restrict__ A, const u16* __restrict__ W,
    const float* __restrict__ bq, const float* __restrict__ bk, const float* __restrict__ bv,
    const float* __restrict__ lBq, const float* __restrict__ lBk, const float* __restrict__ lBv,
    const float* __restrict__ xa, u16* __restrict__ Qb, u16* __restrict__ Kb, u16* __restrict__ Vb){
  __shared__ u16 lds[36864];   // 72 KB: 3 bufs x 24 KB
  int tid = threadIdx.x;
  int l = tid & 63, w = tid >> 6;
  int l15 = l & 15, l4 = l >> 4;
  int wm = w >> 1, wn = w & 1;
  // XCD-aware bijective remap (768 % 8 == 0)
  int bid = blockIdx.x;
  int virt = (bid & 7) * 96 + (bid >> 3);
  int mt = virt & 15, nt = virt >> 4;            // mt 0..15, nt 0..47
  int m0 = mt * 256, n0g = nt * 128;
  int which = nt >> 4;                            // 0=q 1=k 2=v
  int n0 = (nt & 15) * 128;
  const float* bias = which==0 ? bq : which==1 ? bk : bv;
  const float* lB   = which==0 ? lBq : which==1 ? lBk : lBv;
  const float* xs   = xa + which*32768;
  u16* outp         = which==0 ? Qb : which==1 ? Kb : Vb;
  int swz = (which <= 1);
  float oscale = (which == 0) ? QSCALE*LOG2E : 1.0f;

  f32x4 acc[8][4];
  #pragma unroll
  for (int mr=0; mr<8; mr++)
    #pragma unroll
    for (int nr=0; nr<4; nr++) acc[mr][nr] = (f32x4){0.f,0.f,0.f,0.f};

  gemm_core_v7(A + (size_t)m0*2048, W + (size_t)n0g*2048, lds, tid, acc);

  float bvv[4]; float4 lb0[4], lb1[4];
  #pragma unroll
  for (int nr=0; nr<4; nr++){
    int col = n0 + wn*64 + nr*16 + l15;
    bvv[nr] = bias[col];
    lb0[nr] = *(const float4*)(lB + col*8);
    lb1[nr] = *(const float4*)(lB + col*8 + 4);
  }
  #pragma unroll
  for (int mr=0; mr<8; mr++)
    #pragma unroll
    for (int j=0; j<4; j++){
      int r = m0 + wm*128 + mr*16 + l4*4 + j;
      float4 xv0 = *(const float4*)(xs + (size_t)r*8);
      float4 xv1 = *(const float4*)(xs + (size_t)r*8 + 4);
      #pragma unroll
      for (int nr=0; nr<4; nr++){
        int col = n0 + wn*64 + nr*16 + l15;
        float v = acc[mr][nr][j] + bvv[nr] + LORA_SCALE * (
            xv0.x*lb0[nr].x + xv0.y*lb0[nr].y + xv0.z*lb0[nr].z + xv0.w*lb0[nr].w +
            xv1.x*lb1[nr].x + xv1.y*lb1[nr].y + xv1.z*lb1[nr].z + xv1.w*lb1[nr].w);
        v *= oscale;
        int cs = swz ? (col ^ ((r & 7) << 3)) : col;
        outp[(size_t)r*2048 + cs] = f2bf(v);
      }
    }
}

// ---------------- O projection GEMM (256x128 tiles, 256 blocks, fp32 out) ----------------
__global__ __launch_bounds__(256, 2) void gemm_o(
    const u16* __restrict__ A, const u16* __restrict__ W,
    const float* __restrict__ bias, const float* __restrict__ lB,
    const float* __restrict__ xa, float* __restrict__ outp){
  __shared__ u16 lds[36864];   // 72 KB
  int tid = threadIdx.x;
  int l = tid & 63, w = tid >> 6;
  int l15 = l & 15, l4 = l >> 4;
  int wm = w >> 1, wn = w & 1;
  int bid = blockIdx.x;
  int virt = (bid & 7) * 32 + (bid >> 3);        // 256 % 8 == 0, bijective
  int mt = virt & 15, nt = virt >> 4;            // nt 0..15
  int m0 = mt * 256, n0 = nt * 128;

  f32x4 acc[8][4];
  #pragma unroll
  for (int mr=0; mr<8; mr++)
    #pragma unroll
    for (int nr=0; nr<4; nr++) acc[mr][nr] = (f32x4){0.f,0.f,0.f,0.f};

  gemm_core_v7(A + (size_t)m0*2048, W + (size_t)n0*2048, lds, tid, acc);

  float bv[4]; float4 lb0[4], lb1[4];
  #pragma unroll
  for (int nr=0; nr<4; nr++){
    int col = n0 + wn*64 + nr*16 + l15;
    bv[nr] = bias[col];
    lb0[nr] = *(const float4*)(lB + col*8);
    lb1[nr] = *(const float4*)(lB + col*8 + 4);
  }
  #pragma unroll
  for (int mr=0; mr<8; mr++)
    #pragma unroll
    for (int j=0; j<4; j++){
      int r = m0 + wm*128 + mr*16 + l4*4 + j;
      float4 xv0 = *(const float4*)(xa + (size_t)r*8);
      float4 xv1 = *(const float4*)(xa + (size_t)r*8 + 4);
      #pragma unroll
      for (int nr=0; nr<4; nr++){
        int col = n0 + wn*64 + nr*16 + l15;
        float v = acc[mr][nr][j] + bv[nr] + LORA_SCALE * (
            xv0.x*lb0[nr].x + xv0.y*lb0[nr].y + xv0.z*lb0[nr].z + xv0.w*lb0[nr].w +
            xv1.x*lb1[nr].x + xv1.y*lb1[nr].y + xv1.z*lb1[nr].z + xv1.w*lb1[nr].w);
        outp[(size_t)r*2048 + col] = v;
      }
    }
}

// ---------------- V transpose: V[4096][2048] -> Vt[bh][d][s] (kv-swizzled) ----------------
__global__ __launch_bounds__(256) void transpose_v(const u16* __restrict__ V,
                                                   u16* __restrict__ Vt){
  __shared__ u16 tile[64*80];
  int tid = threadIdx.x;
  int f0 = blockIdx.x * 64, m0 = blockIdx.y * 64;
  int i = tid >> 2, j0 = (tid & 3) * 16;
  #pragma unroll
  for (int kk=0; kk<16; kk+=8){
    uint4 u = *(const uint4*)(V + (size_t)(m0 + i)*2048 + f0 + j0 + kk);
    *(uint4*)(tile + i*80 + j0 + kk) = u;
  }
  __syncthreads();
  int j = tid >> 2, i0 = (tid & 3) * 16;
  int b = m0 >> 11, s0 = m0 & 2047;
  int h = f0 >> 7, d = (f0 & 127) + j;
  int c = (d & 7) << 3;
  size_t obase = ((size_t)((b*16 + h)*128 + d)) * 2048 + s0;
  #pragma unroll
  for (int kk=0; kk<16; kk+=8){
    u16 v8[8];
    #pragma unroll
    for (int u2=0; u2<8; ++u2) v8[u2] = tile[(i0+kk+u2)*80 + j];
    *(uint4*)(Vt + obase + ((i0+kk) ^ c)) = *(const uint4*)v8;   // (x^c)+u == (x+u)^c, c%8==0
  }
}

// ---------------- flash attention: QBLK=128, KVBLK=64, 4 waves x 32 q-rows ----------------
__global__ __launch_bounds__(256, 2) void attn_kernel(
    const u16* __restrict__ Q, const u16* __restrict__ K,
    const u16* __restrict__ Vt, u16* __restrict__ ctx){
  __shared__ u16 buf[2][16384];  // per buffer: K [64][128] (8192 u16) then V [128][64]
  __shared__ u16 Psh[4*32*64];   // 16 KB: per-wave P [32 q][64 kv], XOR-swizzled
  int tid = threadIdx.x, w = tid >> 6, lane = tid & 63;
  int l15 = lane & 15, l4 = lane >> 4;
  // T1: XCD-aware remap. 512 blocks, 8 XCDs (wgid%8 = XCD): XCD k gets bh in [4k,4k+4)
  int lin = blockIdx.x;
  int virt = (lin & 7) * 64 + (lin >> 3);
  int qt = virt & 15, bh = virt >> 4;
  int b = bh >> 4, h = bh & 15;
  const u16* Qg = Q + (size_t)(b*2048 + qt*128) * 2048 + h*128;
  const u16* Kg = K + (size_t)(b*2048) * 2048 + h*128;
  const u16* Vg = Vt + (size_t)bh * 128 * 2048;

  // prologue: Q -> buf[1], kv-tile 0 -> buf[0]
  #pragma unroll
  for (int i=0; i<8; ++i){
    int e = (i*256 + tid) * 8;
    int r = e >> 7, cc = e & 127;
    gload16(Qg + (size_t)r*2048 + cc, (char*)buf[1] + i*4096 + w*1024);
  }
  #pragma unroll
  for (int i=0; i<4; ++i){
    int e = (i*256 + tid) * 8;
    int r = e >> 7, cc = e & 127;
    gload16(Kg + (size_t)r*2048 + cc, (char*)buf[0] + i*4096 + w*1024);
    int dd = e >> 6, c2 = e & 63;
    gload16(Vg + (size_t)dd*2048 + c2, (char*)buf[0] + 16384 + i*4096 + w*1024);
  }
  __syncthreads();   // drains vmcnt

  bf16x8 qf[2][4];   // Q rows (pre-scaled by log2e/sqrt(dk)); used as B operand
  #pragma unroll
  for (int mi=0; mi<2; mi++){
    int r = w*32 + mi*16 + l15;
    #pragma unroll
    for (int kb=0; kb<4; kb++){
      int cc = (kb*32 + l4*8) ^ ((r & 7) << 3);
      qf[mi][kb] = *(const bf16x8*)(buf[1] + r*128 + cc);
    }
  }
  __syncthreads();   // all waves done with Q region before it becomes buffer 1

  // O^T accumulator: ctxa[mi][nd] reg j -> d = nd*16 + l4*4 + j, q = mi*16 + l15
  f32x4 ctxa[2][8];
  #pragma unroll
  for (int mi=0; mi<2; mi++)
    #pragma unroll
    for (int nd=0; nd<8; nd++) ctxa[mi][nd] = (f32x4){0.f,0.f,0.f,0.f};
  float mrun[2] = {-3.0e38f, -3.0e38f};
  float lrun[2] = {0.f, 0.f};

  char* PwB = (char*)(Psh + w * (32*64));   // byte base of this wave's P tile
  int psw = (l15 & 7) << 4;                 // byte XOR swizzle for P (row = mi*16+l15)

  for (int t = 0; t < 32; ++t){
    int cur = t & 1;
    const u16* Kc = buf[cur];
    const u16* Vc = buf[cur] + 8192;
    // prefetch next kv tile into the other buffer (latency hides under compute)
    if (t + 1 < 32){
      int kvn = (t + 1) * 64;
      char* bn = (char*)buf[cur ^ 1];
      #pragma unroll
      for (int i=0; i<4; ++i){
        int e = (i*256 + tid) * 8;
        int r = e >> 7, cc = e & 127;
        gload16(Kg + (size_t)(kvn + r)*2048 + cc, bn + i*4096 + w*1024);
        int dd = e >> 6, c2 = e & 63;
        gload16(Vg + (size_t)dd*2048 + kvn + c2, bn + 16384 + i*4096 + w*1024);
      }
    }
    // S^T = mfma(K, Q): lane reg j of s[mi][ni]: kv = ni*16 + l4*4 + j, q = mi*16 + l15
    f32x4 s[2][4];
    #pragma unroll
    for (int mi=0; mi<2; mi++)
      #pragma unroll
      for (int ni=0; ni<4; ni++) s[mi][ni] = (f32x4){0.f,0.f,0.f,0.f};
    __builtin_amdgcn_s_setprio(1);
    #pragma unroll
    for (int kb=0; kb<4; kb++){
      #pragma unroll
      for (int ni=0; ni<4; ni++){
        int r = ni*16 + l15;
        int cc = (kb*32 + l4*8) ^ ((r & 7) << 3);
        bf16x8 kf = *(const bf16x8*)(Kc + r*128 + cc);
        s[0][ni] = __builtin_amdgcn_mfma_f32_16x16x32_bf16(kf, qf[0][kb], s[0][ni], 0, 0, 0);
        s[1][ni] = __builtin_amdgcn_mfma_f32_16x16x32_bf16(kf, qf[1][kb], s[1][ni], 0, 0, 0);
      }
    }
    __builtin_amdgcn_s_setprio(0);
    // in-lane tile max per q-row (16 values) + cross-l4 combine
    float pm[2];
    #pragma unroll
    for (int mi=0; mi<2; mi++){
      float v = s[mi][0][0];
      #pragma unroll
      for (int ni=0; ni<4; ni++)
        #pragma unroll
        for (int j=0; j<4; j++) v = fmaxf(v, s[mi][ni][j]);
      v = fmaxf(v, __shfl_xor(v, 16));
      v = fmaxf(v, __shfl_xor(v, 32));
      pm[mi] = v;
    }
    // T13 defer-max: rescale only when max grows beyond THR (exp2 domain)
    bool need = (pm[0] > mrun[0] + RESCALE_THR) || (pm[1] > mrun[1] + RESCALE_THR);
    if (__any(need)){
      #pragma unroll
      for (int mi=0; mi<2; mi++){
        float mnew = fmaxf(mrun[mi], pm[mi]);
        float cr = exp2f(mrun[mi] - mnew);
        lrun[mi] *= cr;
        mrun[mi] = mnew;
        #pragma unroll
        for (int nd=0; nd<8; nd++) ctxa[mi][nd] *= cr;
      }
    }
    // P = exp2(S - m), pack to bf16, ds_write_b64 (4 consecutive kv per write)
    #pragma unroll
    for (int mi=0; mi<2; mi++){
      float ps = 0.f;
      #pragma unroll
      for (int ni=0; ni<4; ni++){
        float p0 = exp2f(s[mi][ni][0] - mrun[mi]);
        float p1 = exp2f(s[mi][ni][1] - mrun[mi]);
        float p2 = exp2f(s[mi][ni][2] - mrun[mi]);
        float p3 = exp2f(s[mi][ni][3] - mrun[mi]);
        ps += (p0 + p1) + (p2 + p3);
        uint2 pk = {cvt_pk_bf16(p0, p1), cvt_pk_bf16(p2, p3)};
        *(uint2*)(PwB + (mi*16 + l15)*128 + ((ni*32 + l4*8) ^ psw)) = pk;
      }
      ps += __shfl_xor(ps, 16);
      ps += __shfl_xor(ps, 32);
      lrun[mi] += ps;
    }
    // PV (swapped): O^T += mfma(V^T, P); B-frag = P[q=l15(+16mi)][kv=l4*8..+8]
    bf16x8 pb[2][2];
    #pragma unroll
    for (int mi=0; mi<2; mi++)
      #pragma unroll
      for (int kvb=0; kvb<2; kvb++)
        pb[mi][kvb] = *(const bf16x8*)(PwB + (mi*16 + l15)*128 + ((kvb*64 + l4*16) ^ psw));
    __builtin_amdgcn_s_setprio(1);
    #pragma unroll
    for (int nd=0; nd<8; nd++){
      int dd = nd*16 + l15;
      int sw = (dd & 7) << 3;
      #pragma unroll
      for (int kvb=0; kvb<2; kvb++){
        bf16x8 vf = *(const bf16x8*)(Vc + dd*64 + ((kvb*32 + l4*8) ^ sw));
        ctxa[0][nd] = __builtin_amdgcn_mfma_f32_16x16x32_bf16(vf, pb[0][kvb], ctxa[0][nd], 0, 0, 0);
        ctxa[1][nd] = __builtin_amdgcn_mfma_f32_16x16x32_bf16(vf, pb[1][kvb], ctxa[1][nd], 0, 0, 0);
      }
    }
    __builtin_amdgcn_s_setprio(0);
    __syncthreads();   // implicit vmcnt(0): next buffer ready; all waves done with cur
  }
  // epilogue: normalize, transpose through per-wave LDS region, coalesced store
  char* OwB = (char*)buf[0] + w*8192;   // [32 q][128 d] bf16, XOR-swizzled
  #pragma unroll
  for (int mi=0; mi<2; mi++){
    float inv = 1.0f / lrun[mi];
    #pragma unroll
    for (int nd=0; nd<8; nd++){
      f32x4 c = ctxa[mi][nd] * inv;
      uint2 pk = {cvt_pk_bf16(c[0], c[1]), cvt_pk_bf16(c[2], c[3])};
      *(uint2*)(OwB + (mi*16 + l15)*256 + ((nd*32 + l4*8) ^ psw)) = pk;
    }
  }
  #pragma unroll
  for (int i=0; i<8; ++i){
    int row = i*4 + l4;          // 0..31
    int colb = l15*16;           // byte col 0..240
    uint4 v = *(const uint4*)(OwB + row*256 + (colb ^ ((row & 7) << 4)));
    int srow = qt*128 + w*32 + row;
    *(uint4*)(ctx + ((size_t)(b*2048 + srow))*2048 + h*128 + colb/2) = v;
  }
}

// ---------------- launcher ----------------
extern "C" void kernel_launch(void* const* d_in, const int* in_sizes, int n_in,
                              void* d_out, int out_size, void* d_ws, size_t ws_size,
                              hipStream_t stream){
  const float* x  = (const float*)d_in[0];
  const float* Wq = (const float*)d_in[1];  const float* bq = (const float*)d_in[2];
  const float* Aq = (const float*)d_in[3];  const float* Bq = (const float*)d_in[4];
  const float* Wk = (const float*)d_in[5];  const float* bk = (const float*)d_in[6];
  const float* Ak = (const float*)d_in[7];  const float* Bk = (const float*)d_in[8];
  const float* Wv = (const float*)d_in[9];  const float* bv = (const float*)d_in[10];
  const float* Av = (const float*)d_in[11]; const float* Bv = (const float*)d_in[12];
  const float* Wo = (const float*)d_in[13]; const float* bo = (const float*)d_in[14];
  const float* Ao = (const float*)d_in[15]; const float* Bo = (const float*)d_in[16];

  char* ws = (char*)d_ws;
  size_t off = 0;
  u16* xbf  = (u16*)(ws + off); off += (size_t)4096*2048*2;          // 16 MB
  u16* wqkv = (u16*)(ws + off); off += (size_t)3*2048*2048*2;        // 24 MB
  u16* wob  = (u16*)(ws + off); off += (size_t)2048*2048*2;          // 8 MB
  float* xa = (float*)(ws + off); off += (size_t)4*32768*4;          // 4 slabs [4096][8]
  u16* Qb  = (u16*)(ws + off); off += (size_t)4096*2048*2;
  u16* Kb  = (u16*)(ws + off); off += (size_t)4096*2048*2;
  u16* Vb  = (u16*)(ws + off); off += (size_t)4096*2048*2;           // later reused as ctx
  u16* Vtb = (u16*)(ws + off); off += (size_t)4096*2048*2;
  if (ws_size < off) return;   // insufficient scratch — bail (will fail validation loudly)

  cvt_w4<<<8192, 256, 0, stream>>>(Wq, Wk, Wv, Wo, wqkv, wob);
  lora_x_fused<<<1024, 256, 0, stream>>>(x, Aq, Ak, Av, xa, xbf);

  gemm_qkv<<<768, 256, 0, stream>>>(xbf, wqkv, bq, bk, bv, Bq, Bk, Bv, xa, Qb, Kb, Vb);

  transpose_v<<<dim3(32,64), 256, 0, stream>>>(Vb, Vtb);

  attn_kernel<<<512, 256, 0, stream>>>(Qb, Kb, Vtb, Vb);   // ctx -> Vb (V dead after transpose)

  lora_xa_bf16<<<1024, 256, 0, stream>>>(Vb, Ao, xa+98304);

  gemm_o<<<256, 256, 0, stream>>>(Vb, wob, bo, Bo, xa+98304, (float*)d_out);
}